// Round 14
// baseline (3824.217 us; speedup 1.0000x reference)
//
#include <hip/hip_runtime.h>
#include <stdint.h>

typedef __attribute__((ext_vector_type(8))) __bf16 bf16x8;
typedef __attribute__((ext_vector_type(4))) float f32x4;
typedef __attribute__((ext_vector_type(8))) short short8;

__device__ __forceinline__ unsigned short f2bf(float f) {
  unsigned int u = __float_as_uint(f);
  u += 0x7FFFu + ((u >> 16) & 1u);
  return (unsigned short)(u >> 16);
}
__device__ __forceinline__ float bf2f(unsigned short h) {
  return __uint_as_float((unsigned int)h << 16);
}
__device__ __forceinline__ void split2(float v, unsigned short& h, unsigned short& l) {
  h = f2bf(v);
  l = f2bf(v - bf2f(h));
}

#define WAITVM0 asm volatile("s_waitcnt vmcnt(0)" ::: "memory")
#define WAITVM4 asm volatile("s_waitcnt vmcnt(4)" ::: "memory")
#define WAITVM5 asm volatile("s_waitcnt vmcnt(5)" ::: "memory")
#define WAITVM8 asm volatile("s_waitcnt vmcnt(8)" ::: "memory")
#define LGKM0   asm volatile("s_waitcnt lgkmcnt(0)" ::: "memory")
#define SCHED0  __builtin_amdgcn_sched_barrier(0)

// ---------------------------------------------------------------------------
// gemmF: fused multi-layer GEMM chain. Block = 512 thr (8 waves 1x8),
// M_b = 128 rows, N = 512. Inter-layer activation C lives in LDS "Cbuf"
// (16 segments x [128][32] bf16, slot-swizzled = A-fragment layout, 128 KiB).
// Phase-2/3 layers: A from Cbuf with 2-buffer ds_read prefetch (1 kt ahead);
// B direct global->register, 3-set rotation (2 kt ahead) -- all waits
// compiler-derived from register deps; no drains in steady state.
// VAR 0 (dense): phase1 de3 (K=256, A=h3 global, ring-3) -> C; phase2 de4
//   (K=512) -> maxout atomic.
// VAR 1 (rel): phase1 r2 (K=512, A synthesized from G on the fly) -> f32
//   out1 + C; phase2 m1 -> C'; phase3 m2 -> f32 out3.
// ---------------------------------------------------------------------------
template<int VAR>
__global__ __launch_bounds__(512, 1)
void gemmF(const unsigned short* __restrict__ Ag,
           const float* __restrict__ G, const float* __restrict__ gb,
           const unsigned short* __restrict__ W1t, const float* __restrict__ b1,
           const unsigned short* __restrict__ W2t, const float* __restrict__ b2,
           const unsigned short* __restrict__ W3t, const float* __restrict__ b3,
           float* __restrict__ out1, float* __restrict__ out3,
           unsigned int* __restrict__ Omax, int m_base)
{
  extern __shared__ __align__(16) char smem[];   // 131072 B
  short* SS = (short*)smem;
  const int tid = threadIdx.x, lane = tid & 63, w = tid >> 6;
  const int l15 = lane & 15, l4 = lane >> 4;
  const int m0 = blockIdx.x * 128;
  constexpr int K1 = VAR ? 512 : 256;
  constexpr int NT1 = K1 / 32;

  f32x4 acc[8][4];
  #pragma unroll
  for (int a = 0; a < 8; ++a)
    #pragma unroll
    for (int b = 0; b < 4; ++b)
      acc[a][b] = (f32x4){0.f, 0.f, 0.f, 0.f};

  auto MFMA32 = [&](bf16x8* aF, bf16x8* bF) {
    __builtin_amdgcn_s_setprio(1);
    #pragma unroll
    for (int m = 0; m < 8; ++m)
      #pragma unroll
      for (int n = 0; n < 4; ++n)
        acc[m][n] = __builtin_amdgcn_mfma_f32_16x16x32_bf16(aF[m], bF[n], acc[m][n], 0, 0, 0);
    __builtin_amdgcn_s_setprio(0);
  };

  // scatter relu(acc+bias) into Cbuf (A-fragment layout, 16 segs x [128][32])
  auto scatterC = [&](const float* bias) {
    float bv[4];
    #pragma unroll
    for (int ni = 0; ni < 4; ++ni) bv[ni] = bias[w * 64 + ni * 16 + l15];
    #pragma unroll
    for (int mi = 0; mi < 8; ++mi)
      #pragma unroll
      for (int i = 0; i < 4; ++i) {
        int row = mi * 16 + l4 * 4 + i;
        #pragma unroll
        for (int ni = 0; ni < 4; ++ni) {
          int col = w * 64 + ni * 16 + l15;
          int c5 = col & 31;
          int ph = (c5 >> 3) ^ ((row >> 1) & 3);
          SS[(col >> 5) * 4096 + row * 32 + ph * 8 + (col & 7)] =
              (short)f2bf(fmaxf(acc[mi][ni][i] + bv[ni], 0.f));
        }
      }
  };

  // coalesced f32 store of acc+bias (no relu) via LDS bounce, 2 halves
  auto bounceOut = [&](float* dst, const float* bias) {
    float* Bf = (float*)smem;
    #pragma unroll
    for (int h = 0; h < 2; ++h) {
      if ((w >> 2) == h) {
        #pragma unroll
        for (int mi = 0; mi < 8; ++mi)
          #pragma unroll
          for (int i = 0; i < 4; ++i) {
            int row = mi * 16 + l4 * 4 + i;
            #pragma unroll
            for (int ni = 0; ni < 4; ++ni) {
              int colh = (w & 3) * 64 + ni * 16 + l15;
              int sl = colh >> 2;
              int ph = (sl & 56) | ((sl & 7) ^ (row & 7));
              Bf[row * 256 + ph * 4 + (colh & 3)] =
                  acc[mi][ni][i] + bias[w * 64 + ni * 16 + l15];
            }
          }
      }
      __syncthreads();
      #pragma unroll
      for (int s = 0; s < 16; ++s) {
        int p = s * 512 + tid;
        int row = p >> 6, sl = p & 63;
        int ph = (sl & 56) | ((sl & 7) ^ (row & 7));
        f32x4 v = *reinterpret_cast<const f32x4*>(&Bf[row * 256 + ph * 4]);
        *reinterpret_cast<f32x4*>(dst + (size_t)(m0 + row) * 512 + h * 256 + sl * 4) = v;
      }
      __syncthreads();
    }
  };

  // K=512 layer: A from Cbuf (2-buf ds_read prefetch), B global->reg 3-set.
  auto regB_loop = [&](const unsigned short* Wt) {
    #pragma unroll
    for (int a = 0; a < 8; ++a)
      #pragma unroll
      for (int b = 0; b < 4; ++b)
        acc[a][b] = (f32x4){0.f, 0.f, 0.f, 0.f};
    const unsigned short* bp[4];
    #pragma unroll
    for (int n = 0; n < 4; ++n)
      bp[n] = Wt + (size_t)(w * 64 + n * 16 + l15) * 512 + l4 * 8;
    bf16x8 bb[3][4];
    bf16x8 aa[2][8];
    #pragma unroll
    for (int n = 0; n < 4; ++n) {
      bb[0][n] = *reinterpret_cast<const bf16x8*>(bp[n]);
      bb[1][n] = *reinterpret_cast<const bf16x8*>(bp[n] + 32);
    }
    #pragma unroll
    for (int m = 0; m < 8; ++m) {
      int R = m * 16 + l15;
      int ph = l4 ^ ((R >> 1) & 3);
      aa[0][m] = *reinterpret_cast<const bf16x8*>(SS + R * 32 + ph * 8);
    }
    #pragma unroll
    for (int kt = 0; kt < 16; ++kt) {
      if (kt + 2 < 16) {
        #pragma unroll
        for (int n = 0; n < 4; ++n)
          bb[(kt + 2) % 3][n] = *reinterpret_cast<const bf16x8*>(bp[n] + (kt + 2) * 32);
      }
      if (kt + 1 < 16) {
        #pragma unroll
        for (int m = 0; m < 8; ++m) {
          int R = m * 16 + l15;
          int ph = l4 ^ ((R >> 1) & 3);
          aa[(kt + 1) & 1][m] =
              *reinterpret_cast<const bf16x8*>(SS + (kt + 1) * 4096 + R * 32 + ph * 8);
        }
      }
      MFMA32(aa[kt & 1], bb[kt % 3]);
    }
  };

  // ------------------- phase 1: A from global / synthesized -------------------
  const int arow = w * 16 + (lane >> 2);
  const unsigned short* aS = nullptr;
  const float *g1p = nullptr, *g2p = nullptr, *gbp = nullptr;
  if constexpr (VAR == 0) {
    aS = Ag + (size_t)(m0 + arow) * K1 + (((lane & 3) ^ ((arow >> 1) & 3)) * 8);
  } else {
    int r = m0 + arow;
    int b = r & 31, pr = r >> 5;
    int i = pr / 52, j = pr - i * 52;
    g1p = G + (size_t)(i * 32 + b) * 1024 + (lane & 3) * 8;
    g2p = G + (size_t)(j * 32 + b) * 1024 + 512 + (lane & 3) * 8;
    gbp = gb + (lane & 3) * 8;
  }
  const unsigned short* bS1[4];
  #pragma unroll
  for (int o = 0; o < 4; ++o) {
    int br = w * 64 + o * 16 + (lane >> 2);
    bS1[o] = W1t + (size_t)br * K1 + (((lane & 3) ^ ((br >> 1) & 3)) * 8);
  }
  auto stage1 = [&](int kt) {
    short* S = SS + (kt % 3) * 20480;
    if constexpr (VAR == 0) {
      __builtin_amdgcn_global_load_lds(aS + kt * 32, (void*)(S + w * 512), 16, 0, 0);
    } else {
      f32x4 q0 = *reinterpret_cast<const f32x4*>(g1p + kt * 32);
      f32x4 q1 = *reinterpret_cast<const f32x4*>(g1p + kt * 32 + 4);
      f32x4 p0 = *reinterpret_cast<const f32x4*>(g2p + kt * 32);
      f32x4 p1 = *reinterpret_cast<const f32x4*>(g2p + kt * 32 + 4);
      f32x4 c0 = *reinterpret_cast<const f32x4*>(gbp + kt * 32);
      f32x4 c1 = *reinterpret_cast<const f32x4*>(gbp + kt * 32 + 4);
      short8 hv;
      #pragma unroll
      for (int e = 0; e < 4; ++e) {
        hv[e]     = (short)f2bf(fmaxf(q0[e] + p0[e] + c0[e], 0.f));
        hv[4 + e] = (short)f2bf(fmaxf(q1[e] + p1[e] + c1[e], 0.f));
      }
      *reinterpret_cast<short8*>(S + arow * 32 + (((lane & 3) ^ ((arow >> 1) & 3)) * 8)) = hv;
    }
    #pragma unroll
    for (int o = 0; o < 4; ++o)
      __builtin_amdgcn_global_load_lds(bS1[o] + kt * 32,
                                       (void*)(S + 4096 + (w * 64 + o * 16) * 32), 16, 0, 0);
  };

  stage1(0);
  stage1(1);
  #pragma unroll
  for (int kt = 0; kt < NT1; ++kt) {
    if (VAR) { LGKM0; }                  // publish ds_writes of synthesized A
    if (kt < NT1 - 1) { if (VAR) { WAITVM4; } else { WAITVM5; } }
    else { WAITVM0; }
    SCHED0;
    __builtin_amdgcn_s_barrier();
    SCHED0;
    short* S = SS + (kt % 3) * 20480;
    bf16x8 aF[8], bF[4];
    #pragma unroll
    for (int n = 0; n < 4; ++n) {
      int R = w * 64 + n * 16 + l15;
      int ph = l4 ^ ((R >> 1) & 3);
      bF[n] = *reinterpret_cast<const bf16x8*>(S + 4096 + R * 32 + ph * 8);
    }
    #pragma unroll
    for (int m = 0; m < 8; ++m) {
      int R = m * 16 + l15;
      int ph = l4 ^ ((R >> 1) & 3);
      aF[m] = *reinterpret_cast<const bf16x8*>(S + R * 32 + ph * 8);
    }
    if (kt + 2 < NT1) stage1(kt + 2);
    MFMA32(aF, bF);
  }
  __syncthreads();

  if constexpr (VAR == 1) bounceOut(out1, b1);   // rel finals (raw +bias)
  scatterC(b1);                                  // C = relu(acc + b1)
  __syncthreads();

  // ------------------- phase 2 -------------------
  regB_loop(W2t);

  if constexpr (VAR == 0) {
    // fused maxout (de4): 128 rows within one object
    int obj = (m_base + m0) >> 10;
    #pragma unroll
    for (int ni = 0; ni < 4; ++ni) {
      int n = w * 64 + ni * 16 + l15;
      float v = acc[0][ni][0];
      #pragma unroll
      for (int mi = 0; mi < 8; ++mi)
        #pragma unroll
        for (int i = 0; i < 4; ++i)
          v = fmaxf(v, acc[mi][ni][i]);
      v = fmaxf(v + b2[n], 0.0f);
      v = fmaxf(v, __shfl_xor(v, 16));
      v = fmaxf(v, __shfl_xor(v, 32));
      if (l4 == 0)
        atomicMax(&Omax[(size_t)obj * 512 + n], __float_as_uint(v));
    }
    return;
  } else {
    __syncthreads();
    scatterC(b2);                                // C' = relu(m1 + b2)
    __syncthreads();
    regB_loop(W3t);                              // m2
    __syncthreads();
    bounceOut(out3, b3);                         // multi finals
  }
}

// ---------------------------------------------------------------------------
// gemmX: 256x256 tile, BK=32, 4-buffer ring, counted vmcnt (round-10 design).
// Used for se2 (K=64, maxout) and de2 (K=128, bf16-plane out).
// ---------------------------------------------------------------------------
template<int COUT, int K>
__global__ __launch_bounds__(512, 1)
void gemmX(const unsigned short* __restrict__ A,
           const unsigned short* __restrict__ Wt,
           const float* __restrict__ bias,
           void* __restrict__ Cdst,
           unsigned int* __restrict__ Omax,
           int ldc, int ntn, int swz8, int m_base)
{
  extern __shared__ __align__(16) char smem[];   // 131072 B

  int bid = blockIdx.x;
  int mt, nt;
  if (swz8) {
    int xcd = bid & 7;
    int slot = bid >> 3;
    nt = slot % ntn;
    mt = (slot / ntn) * 8 + xcd;
  } else {
    mt = bid / ntn;
    nt = bid - mt * ntn;
  }
  const int m0 = mt * 256, n0 = nt * 256;
  const int tid = threadIdx.x;
  const int lane = tid & 63;
  const int w = tid >> 6;
  const int wm = w >> 2, wn = w & 3;
  const int l15 = lane & 15, l4 = lane >> 4;

  const unsigned short* aSrc[2];
  const unsigned short* bSrc[2];
  #pragma unroll
  for (int o = 0; o < 2; ++o) {
    int ar = w * 32 + o * 16 + (lane >> 2);
    int sc = ((lane & 3) ^ ((ar >> 1) & 3)) * 8;
    aSrc[o] = A + (size_t)(m0 + ar) * K + sc;
    bSrc[o] = Wt + (size_t)(n0 + ar) * K + sc;
  }

  f32x4 acc[8][4];
  #pragma unroll
  for (int a = 0; a < 8; ++a)
    #pragma unroll
    for (int b = 0; b < 4; ++b)
      acc[a][b] = (f32x4){0.f, 0.f, 0.f, 0.f};

  constexpr int NT = K / 32;

  auto STAGE = [&](int kt) {
    short* Ab = (short*)(smem + (size_t)(kt & 3) * 32768);
    short* Bb = Ab + 8192;
    int koff = kt * 32;
    #pragma unroll
    for (int o = 0; o < 2; ++o) {
      int rows = w * 32 + o * 16;
      __builtin_amdgcn_global_load_lds(aSrc[o] + koff, (void*)(Ab + rows * 32), 16, 0, 0);
      __builtin_amdgcn_global_load_lds(bSrc[o] + koff, (void*)(Bb + rows * 32), 16, 0, 0);
    }
  };

  STAGE(0);
  if (NT > 1) STAGE(1);
  if (NT > 2) STAGE(2);

  #pragma unroll
  for (int kt = 0; kt < NT; ++kt) {
    const int beyond = (NT - 1 - kt < 2) ? (NT - 1 - kt) : 2;
    if (beyond == 0)      { WAITVM0; }
    else if (beyond == 1) { WAITVM4; }
    else                  { WAITVM8; }
    SCHED0;
    __builtin_amdgcn_s_barrier();
    SCHED0;

    short* Ab = (short*)(smem + (size_t)(kt & 3) * 32768);
    short* Bb = Ab + 8192;

    bf16x8 aF[8], bF[4];
    #pragma unroll
    for (int n = 0; n < 4; ++n) {
      int R = wn * 64 + n * 16 + l15;
      int ph = l4 ^ ((R >> 1) & 3);
      bF[n] = *reinterpret_cast<const bf16x8*>(&Bb[R * 32 + ph * 8]);
    }
    #pragma unroll
    for (int m = 0; m < 8; ++m) {
      int R = wm * 128 + m * 16 + l15;
      int ph = l4 ^ ((R >> 1) & 3);
      aF[m] = *reinterpret_cast<const bf16x8*>(&Ab[R * 32 + ph * 8]);
    }

    if (kt + 3 <= NT - 1) STAGE(kt + 3);

    __builtin_amdgcn_s_setprio(1);
    #pragma unroll
    for (int m = 0; m < 8; ++m)
      #pragma unroll
      for (int n = 0; n < 4; ++n)
        acc[m][n] = __builtin_amdgcn_mfma_f32_16x16x32_bf16(aF[m], bF[n], acc[m][n], 0, 0, 0);
    __builtin_amdgcn_s_setprio(0);
  }

  __syncthreads();

  if (COUT == 2) {
    int obj = (m_base + m0) >> 10;
    #pragma unroll
    for (int ni = 0; ni < 4; ++ni) {
      int n = n0 + wn * 64 + ni * 16 + l15;
      float v = acc[0][ni][0];
      #pragma unroll
      for (int mi = 0; mi < 8; ++mi)
        #pragma unroll
        for (int i = 0; i < 4; ++i)
          v = fmaxf(v, acc[mi][ni][i]);
      v = fmaxf(v + bias[n], 0.0f);
      v = fmaxf(v, __shfl_xor(v, 16));
      v = fmaxf(v, __shfl_xor(v, 32));
      if (l4 == 0)
        atomicMax(&Omax[(size_t)obj * 512 + n], __float_as_uint(v));
    }
    return;
  }
  // COUT==1: relu bf16 plane via [256][256] bounce
  unsigned short* Bp = (unsigned short*)smem;
  unsigned short* Cp = (unsigned short*)Cdst;
  #pragma unroll
  for (int mi = 0; mi < 8; ++mi)
    #pragma unroll
    for (int i = 0; i < 4; ++i) {
      int row = wm * 128 + mi * 16 + l4 * 4 + i;
      #pragma unroll
      for (int ni = 0; ni < 4; ++ni) {
        int col = wn * 64 + ni * 16 + l15;
        int sl = col >> 3;
        int ph = (sl & 24) | ((sl & 7) ^ (row & 7));
        Bp[row * 256 + ph * 8 + (col & 7)] = f2bf(fmaxf(acc[mi][ni][i] + bias[n0 + col], 0.f));
      }
    }
  __syncthreads();
  #pragma unroll
  for (int s = 0; s < 16; ++s) {
    int p = s * 512 + tid;
    int row = p >> 5, sl = p & 31;
    int ph = (sl & 24) | ((sl & 7) ^ (row & 7));
    short8 v = *reinterpret_cast<const short8*>(&Bp[row * 256 + ph * 8]);
    *reinterpret_cast<short8*>(Cp + (size_t)(m0 + row) * ldc + n0 + sl * 8) = v;
  }
}

// ---------------------------------------------------------------------------
// gemm3: split-2 GEMM (W hi+lo planes), BK=64. Only for the G factor GEMM.
// ---------------------------------------------------------------------------
__global__ __launch_bounds__(256)
void gemm3(const unsigned short* __restrict__ A,
           const unsigned short* __restrict__ Wt,
           const float* __restrict__ bias,
           void* __restrict__ Cdst,
           int M, int K, int ldc, int ntn)
{
  __shared__ __align__(16) short SM[3][128][64];

  int bid = blockIdx.x;
  int mt = bid / ntn, nt = bid - mt * ntn;
  const int m0 = mt * 128, n0 = nt * 128;
  const int tid = threadIdx.x;
  const int lane = tid & 63;
  const int wave = tid >> 6;
  const int wm = wave >> 1, wn = wave & 1;
  const int l15 = lane & 15, l4 = lane >> 4;

  const int rr = tid >> 3;
  const int sp = tid & 7;
  const int sl = sp ^ (rr & 7);
  const int slE = sl * 8;

  const unsigned short* a_p[4];
  const unsigned short* b_p[4];
  #pragma unroll
  for (int c = 0; c < 4; ++c) {
    int rt = c * 32 + rr;
    a_p[c] = A + (size_t)(m0 + rt) * K + slE;
    b_p[c] = Wt + (size_t)(n0 + rt) * 2 * K + slE;
  }

  f32x4 acc[4][4];
  #pragma unroll
  for (int a = 0; a < 4; ++a)
    #pragma unroll
    for (int b = 0; b < 4; ++b)
      acc[a][b] = (f32x4){0.f, 0.f, 0.f, 0.f};

  char* const smb = (char*)&SM[0][0][0];

  for (int k0 = 0; k0 < K; k0 += 64) {
    #pragma unroll
    for (int c = 0; c < 4; ++c) {
      char* lb = smb + c * 4096 + (tid & 192) * 16;
      __builtin_amdgcn_global_load_lds(a_p[c] + k0, (void*)lb, 16, 0, 0);
      __builtin_amdgcn_global_load_lds(b_p[c] + k0, (void*)(lb + 16384), 16, 0, 0);
      __builtin_amdgcn_global_load_lds(b_p[c] + K + k0, (void*)(lb + 32768), 16, 0, 0);
    }
    __syncthreads();
    #pragma unroll
    for (int kf = 0; kf < 2; ++kf) {
      bf16x8 av[4], bh[4], bl[4];
      #pragma unroll
      for (int mi = 0; mi < 4; ++mi) {
        int R = wm * 64 + mi * 16 + l15;
        int sph = (kf * 4 + l4) ^ (R & 7);
        av[mi] = *reinterpret_cast<const bf16x8*>(&SM[0][R][sph * 8]);
      }
      #pragma unroll
      for (int ni = 0; ni < 4; ++ni) {
        int R = wn * 64 + ni * 16 + l15;
        int sph = (kf * 4 + l4) ^ (R & 7);
        bh[ni] = *reinterpret_cast<const bf16x8*>(&SM[1][R][sph * 8]);
        bl[ni] = *reinterpret_cast<const bf16x8*>(&SM[2][R][sph * 8]);
      }
      #pragma unroll
      for (int mi = 0; mi < 4; ++mi)
        #pragma unroll
        for (int ni = 0; ni < 4; ++ni) {
          acc[mi][ni] = __builtin_amdgcn_mfma_f32_16x16x32_bf16(av[mi], bh[ni], acc[mi][ni], 0, 0, 0);
          acc[mi][ni] = __builtin_amdgcn_mfma_f32_16x16x32_bf16(av[mi], bl[ni], acc[mi][ni], 0, 0, 0);
        }
    }
    __syncthreads();
  }

  float* Bf = (float*)smb;
  float* Cf = (float*)Cdst;
  #pragma unroll
  for (int h = 0; h < 2; ++h) {
    if (wm == h) {
      #pragma unroll
      for (int mi = 0; mi < 4; ++mi)
        #pragma unroll
        for (int i = 0; i < 4; ++i) {
          int lr2 = mi * 16 + l4 * 4 + i;
          #pragma unroll
          for (int ni = 0; ni < 4; ++ni) {
            int col = wn * 64 + ni * 16 + l15;
            int off = lr2 * 128 + (((col >> 2) ^ (lr2 & 7)) << 2) + (col & 3);
            Bf[off] = acc[mi][ni][i] + bias[n0 + col];
          }
        }
    }
    __syncthreads();
    #pragma unroll
    for (int s = 0; s < 8; ++s) {
      int p = tid * 8 + s;
      int row = p >> 5, ls = p & 31;
      f32x4 v = *reinterpret_cast<const f32x4*>(&Bf[row * 128 + ((ls ^ (row & 7)) << 2)]);
      *reinterpret_cast<f32x4*>(Cf + (size_t)(m0 + h * 64 + row) * ldc + n0 + ls * 4) = v;
    }
    __syncthreads();
  }
}

// ---------------------------------------------------------------------------
// Per-point MLPs (f32 exact) -> relu'd bf16 planes: s2 [pt][64], h2 [pt][128].
// ---------------------------------------------------------------------------
__global__ __launch_bounds__(256)
void points_kernel(const float* __restrict__ obj6,
                   const float* __restrict__ sW0, const float* __restrict__ sb0,
                   const float* __restrict__ sW1, const float* __restrict__ sb1,
                   const float* __restrict__ dW0, const float* __restrict__ db0,
                   const float* __restrict__ dW1, const float* __restrict__ db1,
                   unsigned short* __restrict__ s2,
                   unsigned short* __restrict__ h2)
{
  __shared__ float sw0[96], sbb0[32], sw1[2048], sbb1[64];
  __shared__ float dw0[384], dbb0[64], dw1[8192], dbb1[128];
  int tid = threadIdx.x;
  for (int i = tid; i < 96; i += 256) sw0[i] = sW0[i];
  if (tid < 32) sbb0[tid] = sb0[tid];
  for (int i = tid; i < 2048; i += 256) sw1[i] = sW1[i];
  if (tid < 64) sbb1[tid] = sb1[tid];
  for (int i = tid; i < 384; i += 256) dw0[i] = dW0[i];
  if (tid < 64) dbb0[tid] = db0[tid];
  for (int i = tid; i < 8192; i += 256) dw1[i] = dW1[i];
  if (tid < 128) dbb1[tid] = db1[tid];
  __syncthreads();

  int pt = blockIdx.x * 256 + tid;
  const float* in = obj6 + (size_t)pt * 6;
  float c0 = in[0], c1 = in[1], c2 = in[2], c3 = in[3], c4 = in[4], c5 = in[5];

  {  // sparse (xyz only)
    float h1[32];
    #pragma unroll
    for (int j = 0; j < 32; ++j)
      h1[j] = fmaxf(c0 * sw0[j] + c1 * sw0[32 + j] + c2 * sw0[64 + j] + sbb0[j], 0.f);
    unsigned short* orow = s2 + (size_t)pt * 64;
    #pragma unroll
    for (int j8 = 0; j8 < 8; ++j8) {
      float a[8];
      #pragma unroll
      for (int e = 0; e < 8; ++e) a[e] = sbb1[j8 * 8 + e];
      #pragma unroll
      for (int i = 0; i < 32; ++i) {
        float hv = h1[i];
        #pragma unroll
        for (int e = 0; e < 8; ++e) a[e] += hv * sw1[i * 64 + j8 * 8 + e];
      }
      short8 o;
      #pragma unroll
      for (int e = 0; e < 8; ++e) o[e] = (short)f2bf(fmaxf(a[e], 0.f));
      *reinterpret_cast<short8*>(orow + j8 * 8) = o;
    }
  }

  {  // dense (all 6 dims)
    float h1[64];
    #pragma unroll
    for (int j = 0; j < 64; ++j) {
      float a = dbb0[j] + c0 * dw0[j] + c1 * dw0[64 + j] + c2 * dw0[128 + j]
              + c3 * dw0[192 + j] + c4 * dw0[256 + j] + c5 * dw0[320 + j];
      h1[j] = fmaxf(a, 0.f);
    }
    unsigned short* orow = h2 + (size_t)pt * 128;
    #pragma unroll
    for (int ch = 0; ch < 4; ++ch) {
      float a[32];
      #pragma unroll
      for (int e = 0; e < 32; ++e) a[e] = dbb1[ch * 32 + e];
      #pragma unroll 8
      for (int i = 0; i < 64; ++i) {
        float hv = h1[i];
        #pragma unroll
        for (int e = 0; e < 32; ++e) a[e] += hv * dw1[i * 128 + ch * 32 + e];
      }
      #pragma unroll
      for (int e8 = 0; e8 < 4; ++e8) {
        short8 o;
        #pragma unroll
        for (int e = 0; e < 8; ++e) o[e] = (short)f2bf(fmaxf(a[e8 * 8 + e], 0.f));
        *reinterpret_cast<short8*>(orow + ch * 32 + e8 * 8) = o;
      }
    }
  }
}

// ---------------------------------------------------------------------------
__global__ void transpose_split(const float* __restrict__ W, unsigned short* __restrict__ Wt,
                                int K, int N)
{
  int id = blockIdx.x * 256 + threadIdx.x;
  if (id >= K * N) return;
  int k = id / N, n = id - k * N;
  unsigned short h, l;
  split2(W[id], h, l);
  Wt[(size_t)n * 2 * K + k] = h;
  Wt[(size_t)n * 2 * K + K + k] = l;
}

__global__ void transpose_cast(const float* __restrict__ W, unsigned short* __restrict__ Wt,
                               int K, int N)
{
  int id = blockIdx.x * 256 + threadIdx.x;
  if (id >= K * N) return;
  int k = id / N, n = id - k * N;
  Wt[(size_t)n * K + k] = f2bf(W[id]);
}

__global__ void zero_kernel(unsigned int* __restrict__ p, int n)
{
  int id = blockIdx.x * 256 + threadIdx.x;
  if (id < n) p[id] = 0u;
}

__global__ void pn_pack_kernel(const float* __restrict__ pnf, unsigned short* __restrict__ pnp)
{
  int id = blockIdx.x * 256 + threadIdx.x;  // 851968
  int o = id >> 9, c = id & 511;
  int b = o / 52, n = o - b * 52;
  pnp[((size_t)(n * 32 + b) << 9) + c] = f2bf(pnf[id]);
}

// ---------------------------------------------------------------------------
__global__ __launch_bounds__(256)
void objmlp_kernel(const float* __restrict__ obj,
                   const float* __restrict__ W0, const float* __restrict__ b0,
                   const float* __restrict__ W1, const float* __restrict__ b1,
                   const float* __restrict__ W2, const float* __restrict__ b2,
                   float* __restrict__ out)
{
  __shared__ float x[512];
  __shared__ float h1[128];
  __shared__ float h2[256];
  int tid = threadIdx.x;
  int r = blockIdx.x;
  int n = r >> 5, b = r & 31;
  int o = b * 52 + n;
  const float* xs = obj + (size_t)o * 512;
  x[tid] = xs[tid];
  x[tid + 256] = xs[tid + 256];
  __syncthreads();
  if (tid < 128) {
    float a = b0[tid];
    #pragma unroll 8
    for (int k = 0; k < 512; ++k) a += x[k] * W0[k * 128 + tid];
    h1[tid] = fmaxf(a, 0.f);
  }
  __syncthreads();
  {
    float a = b1[tid];
    #pragma unroll 8
    for (int k = 0; k < 128; ++k) a += h1[k] * W1[k * 256 + tid];
    h2[tid] = fmaxf(a, 0.f);
  }
  __syncthreads();
  for (int j = tid; j < 607; j += 256) {
    float a = b2[j];
    #pragma unroll 8
    for (int k = 0; k < 256; ++k) a += h2[k] * W2[k * 607 + j];
    out[(size_t)r * 607 + j] = a;
  }
}

// ---------------------------------------------------------------------------
extern "C" void kernel_launch(void* const* d_in, const int* in_sizes, int n_in,
                              void* d_out, int out_size, void* d_ws, size_t ws_size,
                              hipStream_t stream)
{
  const float* objects = (const float*)d_in[1];
  const float* de_W0 = (const float*)d_in[3];  const float* de_b0 = (const float*)d_in[4];
  const float* de_W1 = (const float*)d_in[5];  const float* de_b1 = (const float*)d_in[6];
  const float* de_W2 = (const float*)d_in[7];  const float* de_b2 = (const float*)d_in[8];
  const float* de_W3 = (const float*)d_in[9];  const float* de_b3 = (const float*)d_in[10];
  const float* de_W4 = (const float*)d_in[11]; const float* de_b4 = (const float*)d_in[12];
  const float* se_W0 = (const float*)d_in[13]; const float* se_b0 = (const float*)d_in[14];
  const float* se_W1 = (const float*)d_in[15]; const float* se_b1 = (const float*)d_in[16];
  const float* se_W2 = (const float*)d_in[17]; const float* se_b2 = (const float*)d_in[18];
  const float* om_W0 = (const float*)d_in[19]; const float* om_b0 = (const float*)d_in[20];
  const float* om_W1 = (const float*)d_in[21]; const float* om_b1 = (const float*)d_in[22];
  const float* om_W2 = (const float*)d_in[23]; const float* om_b2 = (const float*)d_in[24];
  const float* r1_W = (const float*)d_in[25];  const float* r1_b = (const float*)d_in[26];
  const float* r2_W = (const float*)d_in[27];  const float* r2_b = (const float*)d_in[28];
  const float* m1_W = (const float*)d_in[29];  const float* m1_b = (const float*)d_in[30];
  const float* m2_W = (const float*)d_in[31];  const float* m2_b = (const float*)d_in[32];
  (void)in_sizes; (void)n_in; (void)out_size; (void)ws_size;

  (void)hipFuncSetAttribute(reinterpret_cast<const void*>(&gemmF<0>),
                            hipFuncAttributeMaxDynamicSharedMemorySize, 131072);
  (void)hipFuncSetAttribute(reinterpret_cast<const void*>(&gemmF<1>),
                            hipFuncAttributeMaxDynamicSharedMemorySize, 131072);
  (void)hipFuncSetAttribute(reinterpret_cast<const void*>(&gemmX<2, 64>),
                            hipFuncAttributeMaxDynamicSharedMemorySize, 131072);
  (void)hipFuncSetAttribute(reinterpret_cast<const void*>(&gemmX<1, 128>),
                            hipFuncAttributeMaxDynamicSharedMemorySize, 131072);

  float* outf = (float*)d_out;
  float* out_obj = outf;                          // [52,32,607]
  float* out_rel = outf + 1010048;                // [52,52,32,512]
  float* out_multi = out_rel + 44302336;

  // ---- workspace (~11 MB) ----
  char* ws = (char*)d_ws;
  size_t off = 0;
  auto alloc = [&](size_t bytes) -> void* {
    void* p = ws + off;
    off += (bytes + 255) & ~(size_t)255;
    return p;
  };
  unsigned short* wt_se2 = (unsigned short*)alloc((size_t)512 * 64 * 2);
  unsigned short* wt_de2 = (unsigned short*)alloc((size_t)256 * 128 * 2);
  unsigned short* wt_de3 = (unsigned short*)alloc((size_t)512 * 256 * 2);
  unsigned short* wt_de4 = (unsigned short*)alloc((size_t)512 * 512 * 2);
  unsigned short* wt_g   = (unsigned short*)alloc((size_t)1024 * 1024 * 2);
  unsigned short* wt_r2  = (unsigned short*)alloc((size_t)512 * 512 * 2);
  unsigned short* wt_m1  = (unsigned short*)alloc((size_t)512 * 512 * 2);
  unsigned short* wt_m2  = (unsigned short*)alloc((size_t)512 * 512 * 2);
  float* zbias = (float*)alloc((size_t)1024 * 4);
  float* Gbuf  = (float*)alloc((size_t)1664 * 1024 * 4);

  // ---- arena inside d_out (rel+multi regions) ----
  char* arena = (char*)out_rel;
  unsigned int* pnmax   = (unsigned int*)(arena);              // 3.4 MB
  float*        obj_f32 = (float*)(arena + 3407872);           // 3.4 MB
  unsigned short* pn_p  = (unsigned short*)(arena + 6815744);  // 1.7 MB
  char* cbuf = arena + 8519680;
  const size_t PC = 212992;                                    // 8 chunks
  unsigned short* s2_c = (unsigned short*)(cbuf);                    // 27.3 MB
  unsigned short* h2_c = (unsigned short*)(cbuf + PC * 128);         // 54.5 MB
  unsigned short* h3_c = (unsigned short*)(cbuf + PC * 384);         // 109  MB

  zero_kernel<<<(2 * 851968) / 256, 256, 0, stream>>>(pnmax, 2 * 851968);
  zero_kernel<<<4, 256, 0, stream>>>((unsigned int*)zbias, 1024);

  auto tsplit = [&](const float* W, unsigned short* Dst, int K, int N) {
    int n = K * N;
    transpose_split<<<(n + 255) / 256, 256, 0, stream>>>(W, Dst, K, N);
  };
  auto tcast = [&](const float* W, unsigned short* Dst, int K, int N) {
    int n = K * N;
    transpose_cast<<<(n + 255) / 256, 256, 0, stream>>>(W, Dst, K, N);
  };
  tcast(se_W2, wt_se2, 64, 512);
  tcast(de_W2, wt_de2, 128, 256);
  tcast(de_W3, wt_de3, 256, 512);
  tcast(de_W4, wt_de4, 512, 512);
  tsplit(r1_W,             wt_g,              512, 512);
  tsplit(r1_W + 512 * 512, wt_g + 512 * 1024, 512, 512);
  tcast(r2_W,  wt_r2, 512, 512);
  tcast(m1_W,  wt_m1, 512, 512);
  tcast(m2_W,  wt_m2, 512, 512);

  // ---- point-cloud chains: 8 chunks x 208 objects (212,992 pts) ----
  for (int c = 0; c < 8; ++c) {
    int base = c * (int)PC;
    points_kernel<<<PC / 256, 256, 0, stream>>>(
        objects + (size_t)base * 6,
        se_W0, se_b0, se_W1, se_b1, de_W0, de_b0, de_W1, de_b1, s2_c, h2_c);
    gemmX<2, 64><<<2 * (PC / 256), 512, 131072, stream>>>(
        s2_c, wt_se2, se_b2, nullptr, pnmax, 512, 2, 1, base);
    gemmX<1, 128><<<(PC / 256), 512, 131072, stream>>>(
        h2_c, wt_de2, de_b2, h3_c, nullptr, 256, 1, 1, 0);
    gemmF<0><<<PC / 128, 512, 131072, stream>>>(
        h3_c, nullptr, nullptr, wt_de3, de_b3, wt_de4, de_b4, nullptr, nullptr,
        nullptr, nullptr, (unsigned int*)obj_f32, base);
  }

  pn_pack_kernel<<<851968 / 256, 256, 0, stream>>>((const float*)pnmax, pn_p);
  objmlp_kernel<<<1664, 256, 0, stream>>>(obj_f32, om_W0, om_b0, om_W1, om_b1,
                                          om_W2, om_b2, out_obj);

  // ---- relation chain ----
  gemm3<<<13 * 8, 256, 0, stream>>>(pn_p, wt_g, zbias, Gbuf, 1664, 512, 1024, 8);
  gemmF<1><<<676, 512, 131072, stream>>>(
      nullptr, Gbuf, r1_b, wt_r2, r2_b, wt_m1, m1_b, wt_m2, m2_b,
      out_rel, out_multi, nullptr, 0);
}

// Round 15
// 3776.385 us; speedup vs baseline: 1.0127x; 1.0127x over previous
//
#include <hip/hip_runtime.h>
#include <stdint.h>

typedef __attribute__((ext_vector_type(8))) __bf16 bf16x8;
typedef __attribute__((ext_vector_type(4))) float f32x4;
typedef __attribute__((ext_vector_type(8))) short short8;

__device__ __forceinline__ unsigned short f2bf(float f) {
  unsigned int u = __float_as_uint(f);
  u += 0x7FFFu + ((u >> 16) & 1u);
  return (unsigned short)(u >> 16);
}
__device__ __forceinline__ float bf2f(unsigned short h) {
  return __uint_as_float((unsigned int)h << 16);
}
__device__ __forceinline__ void split2(float v, unsigned short& h, unsigned short& l) {
  h = f2bf(v);
  l = f2bf(v - bf2f(h));
}

#define WAITVM0 asm volatile("s_waitcnt vmcnt(0)" ::: "memory")
#define WAITVM4 asm volatile("s_waitcnt vmcnt(4)" ::: "memory")
#define WAITVM5 asm volatile("s_waitcnt vmcnt(5)" ::: "memory")
#define WAITVM8 asm volatile("s_waitcnt vmcnt(8)" ::: "memory")
#define LGKM0   asm volatile("s_waitcnt lgkmcnt(0)" ::: "memory")
#define SCHED0  __builtin_amdgcn_sched_barrier(0)

// MFMA on NAMED arrays with compile-time indices (no pointer decay -> no
// scratch spill; round 12-14's lambda-pointer version spilled ~580 MB/disp).
#define MFMA_BLOCK(AV, BV)                                                    \
  do {                                                                        \
    __builtin_amdgcn_s_setprio(1);                                            \
    _Pragma("unroll")                                                         \
    for (int m_ = 0; m_ < 8; ++m_) {                                          \
      _Pragma("unroll")                                                       \
      for (int n_ = 0; n_ < 4; ++n_)                                          \
        acc[m_][n_] = __builtin_amdgcn_mfma_f32_16x16x32_bf16(                \
            AV[m_], BV[n_], acc[m_][n_], 0, 0, 0);                            \
    }                                                                         \
    __builtin_amdgcn_s_setprio(0);                                            \
  } while (0)

#define LOADA_C(dst, kt)                                                      \
  do {                                                                        \
    _Pragma("unroll")                                                         \
    for (int m_ = 0; m_ < 8; ++m_) {                                          \
      int R_ = m_ * 16 + l15;                                                 \
      int ph_ = l4 ^ ((R_ >> 1) & 3);                                         \
      dst[m_] = *reinterpret_cast<const bf16x8*>(                             \
          SS + (kt) * 4096 + R_ * 32 + ph_ * 8);                              \
    }                                                                         \
  } while (0)

#define LOADB_G(dst, kt)                                                      \
  do {                                                                        \
    _Pragma("unroll")                                                         \
    for (int n_ = 0; n_ < 4; ++n_)                                            \
      dst[n_] = *reinterpret_cast<const bf16x8*>(bp[n_] + (kt) * 32);         \
  } while (0)

// K=512 layer: A from Cbuf, B global->reg; named even/odd double buffers.
#define REGB_LAYER(WT)                                                        \
  do {                                                                        \
    _Pragma("unroll")                                                         \
    for (int a_ = 0; a_ < 8; ++a_) {                                          \
      _Pragma("unroll")                                                       \
      for (int b_ = 0; b_ < 4; ++b_)                                          \
        acc[a_][b_] = (f32x4){0.f, 0.f, 0.f, 0.f};                            \
    }                                                                         \
    const unsigned short* bp[4];                                              \
    _Pragma("unroll")                                                         \
    for (int n_ = 0; n_ < 4; ++n_)                                            \
      bp[n_] = (WT) + (size_t)(w * 64 + n_ * 16 + l15) * 512 + l4 * 8;        \
    bf16x8 aE[8], aO[8], bE[4], bO[4];                                        \
    LOADA_C(aE, 0);                                                           \
    LOADB_G(bE, 0);                                                           \
    for (int kk_ = 0; kk_ < 8; ++kk_) {                                       \
      LOADA_C(aO, 2 * kk_ + 1);                                               \
      LOADB_G(bO, 2 * kk_ + 1);                                               \
      MFMA_BLOCK(aE, bE);                                                     \
      if (kk_ < 7) { LOADA_C(aE, 2 * kk_ + 2); LOADB_G(bE, 2 * kk_ + 2); }    \
      MFMA_BLOCK(aO, bO);                                                     \
    }                                                                         \
  } while (0)

// ---------------------------------------------------------------------------
// gemmF: fused multi-layer GEMM chain. Block = 512 thr (8 waves 1x8),
// M_b = 128 rows, N = 512. Inter-layer activation C lives in LDS "Cbuf"
// (16 segments x [128][32] bf16, slot-swizzled = A-fragment layout, 128 KiB).
// VAR 0 (dense): phase1 de3 (K=256, A=h3 global, ring-3) -> C; phase2 de4
//   (K=512) -> maxout atomic.
// VAR 1 (rel): phase1 r2 (K=512, A synthesized from G on the fly) -> f32
//   out1 + C; phase2 m1 -> C'; phase3 m2 -> f32 out3.
// ---------------------------------------------------------------------------
template<int VAR>
__global__ __launch_bounds__(512, 1)
void gemmF(const unsigned short* __restrict__ Ag,
           const float* __restrict__ G, const float* __restrict__ gb,
           const unsigned short* __restrict__ W1t, const float* __restrict__ b1,
           const unsigned short* __restrict__ W2t, const float* __restrict__ b2,
           const unsigned short* __restrict__ W3t, const float* __restrict__ b3,
           float* __restrict__ out1, float* __restrict__ out3,
           unsigned int* __restrict__ Omax, int m_base)
{
  extern __shared__ __align__(16) char smem[];   // 131072 B
  short* SS = (short*)smem;
  const int tid = threadIdx.x, lane = tid & 63, w = tid >> 6;
  const int l15 = lane & 15, l4 = lane >> 4;
  const int m0 = blockIdx.x * 128;
  constexpr int K1 = VAR ? 512 : 256;
  constexpr int NT1 = K1 / 32;

  f32x4 acc[8][4];
  #pragma unroll
  for (int a = 0; a < 8; ++a)
    #pragma unroll
    for (int b = 0; b < 4; ++b)
      acc[a][b] = (f32x4){0.f, 0.f, 0.f, 0.f};

  // scatter relu(acc+bias) into Cbuf (A-fragment layout, 16 segs x [128][32])
  auto scatterC = [&](const float* bias) {
    float bv[4];
    #pragma unroll
    for (int ni = 0; ni < 4; ++ni) bv[ni] = bias[w * 64 + ni * 16 + l15];
    #pragma unroll
    for (int mi = 0; mi < 8; ++mi)
      #pragma unroll
      for (int i = 0; i < 4; ++i) {
        int row = mi * 16 + l4 * 4 + i;
        #pragma unroll
        for (int ni = 0; ni < 4; ++ni) {
          int col = w * 64 + ni * 16 + l15;
          int c5 = col & 31;
          int ph = (c5 >> 3) ^ ((row >> 1) & 3);
          SS[(col >> 5) * 4096 + row * 32 + ph * 8 + (col & 7)] =
              (short)f2bf(fmaxf(acc[mi][ni][i] + bv[ni], 0.f));
        }
      }
  };

  // coalesced f32 store of acc+bias (no relu) via LDS bounce, 2 halves
  auto bounceOut = [&](float* dst, const float* bias) {
    float* Bf = (float*)smem;
    #pragma unroll
    for (int h = 0; h < 2; ++h) {
      if ((w >> 2) == h) {
        #pragma unroll
        for (int mi = 0; mi < 8; ++mi)
          #pragma unroll
          for (int i = 0; i < 4; ++i) {
            int row = mi * 16 + l4 * 4 + i;
            #pragma unroll
            for (int ni = 0; ni < 4; ++ni) {
              int colh = (w & 3) * 64 + ni * 16 + l15;
              int sl = colh >> 2;
              int ph = (sl & 56) | ((sl & 7) ^ (row & 7));
              Bf[row * 256 + ph * 4 + (colh & 3)] =
                  acc[mi][ni][i] + bias[w * 64 + ni * 16 + l15];
            }
          }
      }
      __syncthreads();
      #pragma unroll
      for (int s = 0; s < 16; ++s) {
        int p = s * 512 + tid;
        int row = p >> 6, sl = p & 63;
        int ph = (sl & 56) | ((sl & 7) ^ (row & 7));
        f32x4 v = *reinterpret_cast<const f32x4*>(&Bf[row * 256 + ph * 4]);
        *reinterpret_cast<f32x4*>(dst + (size_t)(m0 + row) * 512 + h * 256 + sl * 4) = v;
      }
      __syncthreads();
    }
  };

  // ------------------- phase 1: A from global / synthesized -------------------
  const int arow = w * 16 + (lane >> 2);
  const unsigned short* aS = nullptr;
  const float *g1p = nullptr, *g2p = nullptr, *gbp = nullptr;
  if constexpr (VAR == 0) {
    aS = Ag + (size_t)(m0 + arow) * K1 + (((lane & 3) ^ ((arow >> 1) & 3)) * 8);
  } else {
    int r = m0 + arow;
    int b = r & 31, pr = r >> 5;
    int i = pr / 52, j = pr - i * 52;
    g1p = G + (size_t)(i * 32 + b) * 1024 + (lane & 3) * 8;
    g2p = G + (size_t)(j * 32 + b) * 1024 + 512 + (lane & 3) * 8;
    gbp = gb + (lane & 3) * 8;
  }
  const unsigned short* bS1[4];
  #pragma unroll
  for (int o = 0; o < 4; ++o) {
    int br = w * 64 + o * 16 + (lane >> 2);
    bS1[o] = W1t + (size_t)br * K1 + (((lane & 3) ^ ((br >> 1) & 3)) * 8);
  }
  auto stage1 = [&](int kt) {
    short* S = SS + (kt % 3) * 20480;
    if constexpr (VAR == 0) {
      __builtin_amdgcn_global_load_lds(aS + kt * 32, (void*)(S + w * 512), 16, 0, 0);
    } else {
      f32x4 q0 = *reinterpret_cast<const f32x4*>(g1p + kt * 32);
      f32x4 q1 = *reinterpret_cast<const f32x4*>(g1p + kt * 32 + 4);
      f32x4 p0 = *reinterpret_cast<const f32x4*>(g2p + kt * 32);
      f32x4 p1 = *reinterpret_cast<const f32x4*>(g2p + kt * 32 + 4);
      f32x4 c0 = *reinterpret_cast<const f32x4*>(gbp + kt * 32);
      f32x4 c1 = *reinterpret_cast<const f32x4*>(gbp + kt * 32 + 4);
      short8 hv;
      #pragma unroll
      for (int e = 0; e < 4; ++e) {
        hv[e]     = (short)f2bf(fmaxf(q0[e] + p0[e] + c0[e], 0.f));
        hv[4 + e] = (short)f2bf(fmaxf(q1[e] + p1[e] + c1[e], 0.f));
      }
      *reinterpret_cast<short8*>(S + arow * 32 + (((lane & 3) ^ ((arow >> 1) & 3)) * 8)) = hv;
    }
    #pragma unroll
    for (int o = 0; o < 4; ++o)
      __builtin_amdgcn_global_load_lds(bS1[o] + kt * 32,
                                       (void*)(S + 4096 + (w * 64 + o * 16) * 32), 16, 0, 0);
  };

  stage1(0);
  stage1(1);
  #pragma unroll
  for (int kt = 0; kt < NT1; ++kt) {
    LGKM0;
    if (kt < NT1 - 1) { if (VAR) { WAITVM4; } else { WAITVM5; } }
    else { WAITVM0; }
    SCHED0;
    __builtin_amdgcn_s_barrier();
    SCHED0;
    short* S = SS + (kt % 3) * 20480;
    bf16x8 aF[8], bF[4];
    #pragma unroll
    for (int n = 0; n < 4; ++n) {
      int R = w * 64 + n * 16 + l15;
      int ph = l4 ^ ((R >> 1) & 3);
      bF[n] = *reinterpret_cast<const bf16x8*>(S + 4096 + R * 32 + ph * 8);
    }
    #pragma unroll
    for (int m = 0; m < 8; ++m) {
      int R = m * 16 + l15;
      int ph = l4 ^ ((R >> 1) & 3);
      aF[m] = *reinterpret_cast<const bf16x8*>(S + R * 32 + ph * 8);
    }
    if (kt + 2 < NT1) stage1(kt + 2);
    MFMA_BLOCK(aF, bF);
  }
  __syncthreads();

  if constexpr (VAR == 1) bounceOut(out1, b1);   // rel finals (raw +bias)
  scatterC(b1);                                  // C = relu(acc + b1)
  __syncthreads();

  // ------------------- phase 2 -------------------
  REGB_LAYER(W2t);

  if constexpr (VAR == 0) {
    // fused maxout (de4): 128 rows within one object
    int obj = (m_base + m0) >> 10;
    #pragma unroll
    for (int ni = 0; ni < 4; ++ni) {
      int n = w * 64 + ni * 16 + l15;
      float v = acc[0][ni][0];
      #pragma unroll
      for (int mi = 0; mi < 8; ++mi)
        #pragma unroll
        for (int i = 0; i < 4; ++i)
          v = fmaxf(v, acc[mi][ni][i]);
      v = fmaxf(v + b2[n], 0.0f);
      v = fmaxf(v, __shfl_xor(v, 16));
      v = fmaxf(v, __shfl_xor(v, 32));
      if (l4 == 0)
        atomicMax(&Omax[(size_t)obj * 512 + n], __float_as_uint(v));
    }
    return;
  } else {
    __syncthreads();
    scatterC(b2);                                // C' = relu(m1 + b2)
    __syncthreads();
    REGB_LAYER(W3t);                             // m2
    __syncthreads();
    bounceOut(out3, b3);                         // multi finals
  }
}

// ---------------------------------------------------------------------------
// gemmX: 256x256 tile, BK=32, 4-buffer ring, counted vmcnt (round-10 design).
// Used for se2 (K=64, maxout) and de2 (K=128, bf16-plane out).
// ---------------------------------------------------------------------------
template<int COUT, int K>
__global__ __launch_bounds__(512, 1)
void gemmX(const unsigned short* __restrict__ A,
           const unsigned short* __restrict__ Wt,
           const float* __restrict__ bias,
           void* __restrict__ Cdst,
           unsigned int* __restrict__ Omax,
           int ldc, int ntn, int swz8, int m_base)
{
  extern __shared__ __align__(16) char smem[];   // 131072 B

  int bid = blockIdx.x;
  int mt, nt;
  if (swz8) {
    int xcd = bid & 7;
    int slot = bid >> 3;
    nt = slot % ntn;
    mt = (slot / ntn) * 8 + xcd;
  } else {
    mt = bid / ntn;
    nt = bid - mt * ntn;
  }
  const int m0 = mt * 256, n0 = nt * 256;
  const int tid = threadIdx.x;
  const int lane = tid & 63;
  const int w = tid >> 6;
  const int wm = w >> 2, wn = w & 3;
  const int l15 = lane & 15, l4 = lane >> 4;

  const unsigned short* aSrc[2];
  const unsigned short* bSrc[2];
  #pragma unroll
  for (int o = 0; o < 2; ++o) {
    int ar = w * 32 + o * 16 + (lane >> 2);
    int sc = ((lane & 3) ^ ((ar >> 1) & 3)) * 8;
    aSrc[o] = A + (size_t)(m0 + ar) * K + sc;
    bSrc[o] = Wt + (size_t)(n0 + ar) * K + sc;
  }

  f32x4 acc[8][4];
  #pragma unroll
  for (int a = 0; a < 8; ++a)
    #pragma unroll
    for (int b = 0; b < 4; ++b)
      acc[a][b] = (f32x4){0.f, 0.f, 0.f, 0.f};

  constexpr int NT = K / 32;

  auto STAGE = [&](int kt) {
    short* Ab = (short*)(smem + (size_t)(kt & 3) * 32768);
    short* Bb = Ab + 8192;
    int koff = kt * 32;
    #pragma unroll
    for (int o = 0; o < 2; ++o) {
      int rows = w * 32 + o * 16;
      __builtin_amdgcn_global_load_lds(aSrc[o] + koff, (void*)(Ab + rows * 32), 16, 0, 0);
      __builtin_amdgcn_global_load_lds(bSrc[o] + koff, (void*)(Bb + rows * 32), 16, 0, 0);
    }
  };

  STAGE(0);
  if (NT > 1) STAGE(1);
  if (NT > 2) STAGE(2);

  #pragma unroll
  for (int kt = 0; kt < NT; ++kt) {
    const int beyond = (NT - 1 - kt < 2) ? (NT - 1 - kt) : 2;
    if (beyond == 0)      { WAITVM0; }
    else if (beyond == 1) { WAITVM4; }
    else                  { WAITVM8; }
    SCHED0;
    __builtin_amdgcn_s_barrier();
    SCHED0;

    short* Ab = (short*)(smem + (size_t)(kt & 3) * 32768);
    short* Bb = Ab + 8192;

    bf16x8 aF[8], bF[4];
    #pragma unroll
    for (int n = 0; n < 4; ++n) {
      int R = wn * 64 + n * 16 + l15;
      int ph = l4 ^ ((R >> 1) & 3);
      bF[n] = *reinterpret_cast<const bf16x8*>(&Bb[R * 32 + ph * 8]);
    }
    #pragma unroll
    for (int m = 0; m < 8; ++m) {
      int R = wm * 128 + m * 16 + l15;
      int ph = l4 ^ ((R >> 1) & 3);
      aF[m] = *reinterpret_cast<const bf16x8*>(&Ab[R * 32 + ph * 8]);
    }

    if (kt + 3 <= NT - 1) STAGE(kt + 3);

    MFMA_BLOCK(aF, bF);
  }

  __syncthreads();

  if (COUT == 2) {
    int obj = (m_base + m0) >> 10;
    #pragma unroll
    for (int ni = 0; ni < 4; ++ni) {
      int n = n0 + wn * 64 + ni * 16 + l15;
      float v = acc[0][ni][0];
      #pragma unroll
      for (int mi = 0; mi < 8; ++mi)
        #pragma unroll
        for (int i = 0; i < 4; ++i)
          v = fmaxf(v, acc[mi][ni][i]);
      v = fmaxf(v + bias[n], 0.0f);
      v = fmaxf(v, __shfl_xor(v, 16));
      v = fmaxf(v, __shfl_xor(v, 32));
      if (l4 == 0)
        atomicMax(&Omax[(size_t)obj * 512 + n], __float_as_uint(v));
    }
    return;
  }
  // COUT==1: relu bf16 plane via [256][256] bounce
  unsigned short* Bp = (unsigned short*)smem;
  unsigned short* Cp = (unsigned short*)Cdst;
  #pragma unroll
  for (int mi = 0; mi < 8; ++mi)
    #pragma unroll
    for (int i = 0; i < 4; ++i) {
      int row = wm * 128 + mi * 16 + l4 * 4 + i;
      #pragma unroll
      for (int ni = 0; ni < 4; ++ni) {
        int col = wn * 64 + ni * 16 + l15;
        int sl = col >> 3;
        int ph = (sl & 24) | ((sl & 7) ^ (row & 7));
        Bp[row * 256 + ph * 8 + (col & 7)] = f2bf(fmaxf(acc[mi][ni][i] + bias[n0 + col], 0.f));
      }
    }
  __syncthreads();
  #pragma unroll
  for (int s = 0; s < 16; ++s) {
    int p = s * 512 + tid;
    int row = p >> 5, sl = p & 31;
    int ph = (sl & 24) | ((sl & 7) ^ (row & 7));
    short8 v = *reinterpret_cast<const short8*>(&Bp[row * 256 + ph * 8]);
    *reinterpret_cast<short8*>(Cp + (size_t)(m0 + row) * ldc + n0 + sl * 8) = v;
  }
}

// ---------------------------------------------------------------------------
// gemm3: split-2 GEMM (W hi+lo planes), BK=64. Only for the G factor GEMM.
// ---------------------------------------------------------------------------
__global__ __launch_bounds__(256)
void gemm3(const unsigned short* __restrict__ A,
           const unsigned short* __restrict__ Wt,
           const float* __restrict__ bias,
           void* __restrict__ Cdst,
           int M, int K, int ldc, int ntn)
{
  __shared__ __align__(16) short SM[3][128][64];

  int bid = blockIdx.x;
  int mt = bid / ntn, nt = bid - mt * ntn;
  const int m0 = mt * 128, n0 = nt * 128;
  const int tid = threadIdx.x;
  const int lane = tid & 63;
  const int wave = tid >> 6;
  const int wm = wave >> 1, wn = wave & 1;
  const int l15 = lane & 15, l4 = lane >> 4;

  const int rr = tid >> 3;
  const int sp = tid & 7;
  const int sl = sp ^ (rr & 7);
  const int slE = sl * 8;

  const unsigned short* a_p[4];
  const unsigned short* b_p[4];
  #pragma unroll
  for (int c = 0; c < 4; ++c) {
    int rt = c * 32 + rr;
    a_p[c] = A + (size_t)(m0 + rt) * K + slE;
    b_p[c] = Wt + (size_t)(n0 + rt) * 2 * K + slE;
  }

  f32x4 acc[4][4];
  #pragma unroll
  for (int a = 0; a < 4; ++a)
    #pragma unroll
    for (int b = 0; b < 4; ++b)
      acc[a][b] = (f32x4){0.f, 0.f, 0.f, 0.f};

  char* const smb = (char*)&SM[0][0][0];

  for (int k0 = 0; k0 < K; k0 += 64) {
    #pragma unroll
    for (int c = 0; c < 4; ++c) {
      char* lb = smb + c * 4096 + (tid & 192) * 16;
      __builtin_amdgcn_global_load_lds(a_p[c] + k0, (void*)lb, 16, 0, 0);
      __builtin_amdgcn_global_load_lds(b_p[c] + k0, (void*)(lb + 16384), 16, 0, 0);
      __builtin_amdgcn_global_load_lds(b_p[c] + K + k0, (void*)(lb + 32768), 16, 0, 0);
    }
    __syncthreads();
    #pragma unroll
    for (int kf = 0; kf < 2; ++kf) {
      bf16x8 av[4], bh[4], bl[4];
      #pragma unroll
      for (int mi = 0; mi < 4; ++mi) {
        int R = wm * 64 + mi * 16 + l15;
        int sph = (kf * 4 + l4) ^ (R & 7);
        av[mi] = *reinterpret_cast<const bf16x8*>(&SM[0][R][sph * 8]);
      }
      #pragma unroll
      for (int ni = 0; ni < 4; ++ni) {
        int R = wn * 64 + ni * 16 + l15;
        int sph = (kf * 4 + l4) ^ (R & 7);
        bh[ni] = *reinterpret_cast<const bf16x8*>(&SM[1][R][sph * 8]);
        bl[ni] = *reinterpret_cast<const bf16x8*>(&SM[2][R][sph * 8]);
      }
      #pragma unroll
      for (int mi = 0; mi < 4; ++mi)
        #pragma unroll
        for (int ni = 0; ni < 4; ++ni) {
          acc[mi][ni] = __builtin_amdgcn_mfma_f32_16x16x32_bf16(av[mi], bh[ni], acc[mi][ni], 0, 0, 0);
          acc[mi][ni] = __builtin_amdgcn_mfma_f32_16x16x32_bf16(av[mi], bl[ni], acc[mi][ni], 0, 0, 0);
        }
    }
    __syncthreads();
  }

  float* Bf = (float*)smb;
  float* Cf = (float*)Cdst;
  #pragma unroll
  for (int h = 0; h < 2; ++h) {
    if (wm == h) {
      #pragma unroll
      for (int mi = 0; mi < 4; ++mi)
        #pragma unroll
        for (int i = 0; i < 4; ++i) {
          int lr2 = mi * 16 + l4 * 4 + i;
          #pragma unroll
          for (int ni = 0; ni < 4; ++ni) {
            int col = wn * 64 + ni * 16 + l15;
            int off = lr2 * 128 + (((col >> 2) ^ (lr2 & 7)) << 2) + (col & 3);
            Bf[off] = acc[mi][ni][i] + bias[n0 + col];
          }
        }
    }
    __syncthreads();
    #pragma unroll
    for (int s = 0; s < 8; ++s) {
      int p = tid * 8 + s;
      int row = p >> 5, ls = p & 31;
      f32x4 v = *reinterpret_cast<const f32x4*>(&Bf[row * 128 + ((ls ^ (row & 7)) << 2)]);
      *reinterpret_cast<f32x4*>(Cf + (size_t)(m0 + h * 64 + row) * ldc + n0 + ls * 4) = v;
    }
    __syncthreads();
  }
}

// ---------------------------------------------------------------------------
// Per-point MLPs (f32 exact) -> relu'd bf16 planes: s2 [pt][64], h2 [pt][128].
// ---------------------------------------------------------------------------
__global__ __launch_bounds__(256)
void points_kernel(const float* __restrict__ obj6,
                   const float* __restrict__ sW0, const float* __restrict__ sb0,
                   const float* __restrict__ sW1, const float* __restrict__ sb1,
                   const float* __restrict__ dW0, const float* __restrict__ db0,
                   const float* __restrict__ dW1, const float* __restrict__ db1,
                   unsigned short* __restrict__ s2,
                   unsigned short* __restrict__ h2)
{
  __shared__ float sw0[96], sbb0[32], sw1[2048], sbb1[64];
  __shared__ float dw0[384], dbb0[64], dw1[8192], dbb1[128];
  int tid = threadIdx.x;
  for (int i = tid; i < 96; i += 256) sw0[i] = sW0[i];
  if (tid < 32) sbb0[tid] = sb0[tid];
  for (int i = tid; i < 2048; i += 256) sw1[i] = sW1[i];
  if (tid < 64) sbb1[tid] = sb1[tid];
  for (int i = tid; i < 384; i += 256) dw0[i] = dW0[i];
  if (tid < 64) dbb0[tid] = db0[tid];
  for (int i = tid; i < 8192; i += 256) dw1[i] = dW1[i];
  if (tid < 128) dbb1[tid] = db1[tid];
  __syncthreads();

  int pt = blockIdx.x * 256 + tid;
  const float* in = obj6 + (size_t)pt * 6;
  float c0 = in[0], c1 = in[1], c2 = in[2], c3 = in[3], c4 = in[4], c5 = in[5];

  {  // sparse (xyz only)
    float h1[32];
    #pragma unroll
    for (int j = 0; j < 32; ++j)
      h1[j] = fmaxf(c0 * sw0[j] + c1 * sw0[32 + j] + c2 * sw0[64 + j] + sbb0[j], 0.f);
    unsigned short* orow = s2 + (size_t)pt * 64;
    #pragma unroll
    for (int j8 = 0; j8 < 8; ++j8) {
      float a[8];
      #pragma unroll
      for (int e = 0; e < 8; ++e) a[e] = sbb1[j8 * 8 + e];
      #pragma unroll
      for (int i = 0; i < 32; ++i) {
        float hv = h1[i];
        #pragma unroll
        for (int e = 0; e < 8; ++e) a[e] += hv * sw1[i * 64 + j8 * 8 + e];
      }
      short8 o;
      #pragma unroll
      for (int e = 0; e < 8; ++e) o[e] = (short)f2bf(fmaxf(a[e], 0.f));
      *reinterpret_cast<short8*>(orow + j8 * 8) = o;
    }
  }

  {  // dense (all 6 dims)
    float h1[64];
    #pragma unroll
    for (int j = 0; j < 64; ++j) {
      float a = dbb0[j] + c0 * dw0[j] + c1 * dw0[64 + j] + c2 * dw0[128 + j]
              + c3 * dw0[192 + j] + c4 * dw0[256 + j] + c5 * dw0[320 + j];
      h1[j] = fmaxf(a, 0.f);
    }
    unsigned short* orow = h2 + (size_t)pt * 128;
    #pragma unroll
    for (int ch = 0; ch < 4; ++ch) {
      float a[32];
      #pragma unroll
      for (int e = 0; e < 32; ++e) a[e] = dbb1[ch * 32 + e];
      #pragma unroll 8
      for (int i = 0; i < 64; ++i) {
        float hv = h1[i];
        #pragma unroll
        for (int e = 0; e < 32; ++e) a[e] += hv * dw1[i * 128 + ch * 32 + e];
      }
      #pragma unroll
      for (int e8 = 0; e8 < 4; ++e8) {
        short8 o;
        #pragma unroll
        for (int e = 0; e < 8; ++e) o[e] = (short)f2bf(fmaxf(a[e8 * 8 + e], 0.f));
        *reinterpret_cast<short8*>(orow + ch * 32 + e8 * 8) = o;
      }
    }
  }
}

// ---------------------------------------------------------------------------
__global__ void transpose_split(const float* __restrict__ W, unsigned short* __restrict__ Wt,
                                int K, int N)
{
  int id = blockIdx.x * 256 + threadIdx.x;
  if (id >= K * N) return;
  int k = id / N, n = id - k * N;
  unsigned short h, l;
  split2(W[id], h, l);
  Wt[(size_t)n * 2 * K + k] = h;
  Wt[(size_t)n * 2 * K + K + k] = l;
}

__global__ void transpose_cast(const float* __restrict__ W, unsigned short* __restrict__ Wt,
                               int K, int N)
{
  int id = blockIdx.x * 256 + threadIdx.x;
  if (id >= K * N) return;
  int k = id / N, n = id - k * N;
  Wt[(size_t)n * K + k] = f2bf(W[id]);
}

__global__ void zero_kernel(unsigned int* __restrict__ p, int n)
{
  int id = blockIdx.x * 256 + threadIdx.x;
  if (id < n) p[id] = 0u;
}

__global__ void pn_pack_kernel(const float* __restrict__ pnf, unsigned short* __restrict__ pnp)
{
  int id = blockIdx.x * 256 + threadIdx.x;  // 851968
  int o = id >> 9, c = id & 511;
  int b = o / 52, n = o - b * 52;
  pnp[((size_t)(n * 32 + b) << 9) + c] = f2bf(pnf[id]);
}

// ---------------------------------------------------------------------------
__global__ __launch_bounds__(256)
void objmlp_kernel(const float* __restrict__ obj,
                   const float* __restrict__ W0, const float* __restrict__ b0,
                   const float* __restrict__ W1, const float* __restrict__ b1,
                   const float* __restrict__ W2, const float* __restrict__ b2,
                   float* __restrict__ out)
{
  __shared__ float x[512];
  __shared__ float h1[128];
  __shared__ float h2[256];
  int tid = threadIdx.x;
  int r = blockIdx.x;
  int n = r >> 5, b = r & 31;
  int o = b * 52 + n;
  const float* xs = obj + (size_t)o * 512;
  x[tid] = xs[tid];
  x[tid + 256] = xs[tid + 256];
  __syncthreads();
  if (tid < 128) {
    float a = b0[tid];
    #pragma unroll 8
    for (int k = 0; k < 512; ++k) a += x[k] * W0[k * 128 + tid];
    h1[tid] = fmaxf(a, 0.f);
  }
  __syncthreads();
  {
    float a = b1[tid];
    #pragma unroll 8
    for (int k = 0; k < 128; ++k) a += h1[k] * W1[k * 256 + tid];
    h2[tid] = fmaxf(a, 0.f);
  }
  __syncthreads();
  for (int j = tid; j < 607; j += 256) {
    float a = b2[j];
    #pragma unroll 8
    for (int k = 0; k < 256; ++k) a += h2[k] * W2[k * 607 + j];
    out[(size_t)r * 607 + j] = a;
  }
}

// ---------------------------------------------------------------------------
extern "C" void kernel_launch(void* const* d_in, const int* in_sizes, int n_in,
                              void* d_out, int out_size, void* d_ws, size_t ws_size,
                              hipStream_t stream)
{
  const float* objects = (const float*)d_in[1];
  const float* de_W0 = (const float*)d_in[3];  const float* de_b0 = (const float*)d_in[4];
  const float* de_W1 = (const float*)d_in[5];  const float* de_b1 = (const float*)d_in[6];
  const float* de_W2 = (const float*)d_in[7];  const float* de_b2 = (const float*)d_in[8];
  const float* de_W3 = (const float*)d_in[9];  const float* de_b3 = (const float*)d_in[10];
  const float* de_W4 = (const float*)d_in[11]; const float* de_b4 = (const float*)d_in[12];
  const float* se_W0 = (const float*)d_in[13]; const float* se_b0 = (const float*)d_in[14];
  const float* se_W1 = (const float*)d_in[15]; const float* se_b1 = (const float*)d_in[16];
  const float* se_W2 = (const float*)d_in[17]; const float* se_b2 = (const float*)d_in[18];
  const float* om_W0 = (const float*)d_in[19]; const float* om_b0 = (const float*)d_in[20];
  const float* om_W1 = (const float*)d_in[21]; const float* om_b1 = (const float*)d_in[22];
  const float* om_W2 = (const float*)d_in[23]; const float* om_b2 = (const float*)d_in[24];
  const float* r1_W = (const float*)d_in[25];  const float* r1_b = (const float*)d_in[26];
  const float* r2_W = (const float*)d_in[27];  const float* r2_b = (const float*)d_in[28];
  const float* m1_W = (const float*)d_in[29];  const float* m1_b = (const float*)d_in[30];
  const float* m2_W = (const float*)d_in[31];  const float* m2_b = (const float*)d_in[32];
  (void)in_sizes; (void)n_in; (void)out_size; (void)ws_size;

  (void)hipFuncSetAttribute(reinterpret_cast<const void*>(&gemmF<0>),
                            hipFuncAttributeMaxDynamicSharedMemorySize, 131072);
  (void)hipFuncSetAttribute(reinterpret_cast<const void*>(&gemmF<1>),
                            hipFuncAttributeMaxDynamicSharedMemorySize, 131072);
  (void)hipFuncSetAttribute(reinterpret_cast<const void*>(&gemmX<2, 64>),
                            hipFuncAttributeMaxDynamicSharedMemorySize, 131072);
  (void)hipFuncSetAttribute(reinterpret_cast<const void*>(&gemmX<1, 128>),
                            hipFuncAttributeMaxDynamicSharedMemorySize, 131072);

  float* outf = (float*)d_out;
  float* out_obj = outf;                          // [52,32,607]
  float* out_rel = outf + 1010048;                // [52,52,32,512]
  float* out_multi = out_rel + 44302336;

  // ---- workspace (~11 MB) ----
  char* ws = (char*)d_ws;
  size_t off = 0;
  auto alloc = [&](size_t bytes) -> void* {
    void* p = ws + off;
    off += (bytes + 255) & ~(size_t)255;
    return p;
  };
  unsigned short* wt_se2 = (unsigned short*)alloc((size_t)512 * 64 * 2);
  unsigned short* wt_de2 = (unsigned short*)alloc((size_t)256 * 128 * 2);
  unsigned short* wt_de3 = (unsigned short*)alloc((size_t)512 * 256 * 2);
  unsigned short* wt_de4 = (unsigned short*)alloc((size_t)512 * 512 * 2);
  unsigned short* wt_g   = (unsigned short*)alloc((size_t)1024 * 1024 * 2);
  unsigned short* wt_r2  = (unsigned short*)alloc((size_t)512 * 512 * 2);
  unsigned short* wt_m1  = (unsigned short*)alloc((size_t)512 * 512 * 2);
  unsigned short* wt_m2  = (unsigned short*)alloc((size_t)512 * 512 * 2);
  float* zbias = (float*)alloc((size_t)1024 * 4);
  float* Gbuf  = (float*)alloc((size_t)1664 * 1024 * 4);

  // ---- arena inside d_out (rel+multi regions) ----
  char* arena = (char*)out_rel;
  unsigned int* pnmax   = (unsigned int*)(arena);              // 3.4 MB
  float*        obj_f32 = (float*)(arena + 3407872);           // 3.4 MB
  unsigned short* pn_p  = (unsigned short*)(arena + 6815744);  // 1.7 MB
  char* cbuf = arena + 8519680;
  const size_t PC = 212992;                                    // 8 chunks
  unsigned short* s2_c = (unsigned short*)(cbuf);                    // 27.3 MB
  unsigned short* h2_c = (unsigned short*)(cbuf + PC * 128);         // 54.5 MB
  unsigned short* h3_c = (unsigned short*)(cbuf + PC * 384);         // 109  MB

  zero_kernel<<<(2 * 851968) / 256, 256, 0, stream>>>(pnmax, 2 * 851968);
  zero_kernel<<<4, 256, 0, stream>>>((unsigned int*)zbias, 1024);

  auto tsplit = [&](const float* W, unsigned short* Dst, int K, int N) {
    int n = K * N;
    transpose_split<<<(n + 255) / 256, 256, 0, stream>>>(W, Dst, K, N);
  };
  auto tcast = [&](const float* W, unsigned short* Dst, int K, int N) {
    int n = K * N;
    transpose_cast<<<(n + 255) / 256, 256, 0, stream>>>(W, Dst, K, N);
  };
  tcast(se_W2, wt_se2, 64, 512);
  tcast(de_W2, wt_de2, 128, 256);
  tcast(de_W3, wt_de3, 256, 512);
  tcast(de_W4, wt_de4, 512, 512);
  tsplit(r1_W,             wt_g,              512, 512);
  tsplit(r1_W + 512 * 512, wt_g + 512 * 1024, 512, 512);
  tcast(r2_W,  wt_r2, 512, 512);
  tcast(m1_W,  wt_m1, 512, 512);
  tcast(m2_W,  wt_m2, 512, 512);

  // ---- point-cloud chains: 8 chunks x 208 objects (212,992 pts) ----
  for (int c = 0; c < 8; ++c) {
    int base = c * (int)PC;
    points_kernel<<<PC / 256, 256, 0, stream>>>(
        objects + (size_t)base * 6,
        se_W0, se_b0, se_W1, se_b1, de_W0, de_b0, de_W1, de_b1, s2_c, h2_c);
    gemmX<2, 64><<<2 * (PC / 256), 512, 131072, stream>>>(
        s2_c, wt_se2, se_b2, nullptr, pnmax, 512, 2, 1, base);
    gemmX<1, 128><<<(PC / 256), 512, 131072, stream>>>(
        h2_c, wt_de2, de_b2, h3_c, nullptr, 256, 1, 1, 0);
    gemmF<0><<<PC / 128, 512, 131072, stream>>>(
        h3_c, nullptr, nullptr, wt_de3, de_b3, wt_de4, de_b4, nullptr, nullptr,
        nullptr, nullptr, (unsigned int*)obj_f32, base);
  }

  pn_pack_kernel<<<851968 / 256, 256, 0, stream>>>((const float*)pnmax, pn_p);
  objmlp_kernel<<<1664, 256, 0, stream>>>(obj_f32, om_W0, om_b0, om_W1, om_b1,
                                          om_W2, om_b2, out_obj);

  // ---- relation chain ----
  gemm3<<<13 * 8, 256, 0, stream>>>(pn_p, wt_g, zbias, Gbuf, 1664, 512, 1024, 8);
  gemmF<1><<<676, 512, 131072, stream>>>(
      nullptr, Gbuf, r1_b, wt_r2, r2_b, wt_m1, m1_b, wt_m2, m2_b,
      out_rel, out_multi, nullptr, 0);
}

// Round 16
// 3753.480 us; speedup vs baseline: 1.0188x; 1.0061x over previous
//
#include <hip/hip_runtime.h>
#include <stdint.h>

typedef __attribute__((ext_vector_type(8))) __bf16 bf16x8;
typedef __attribute__((ext_vector_type(4))) float f32x4;
typedef __attribute__((ext_vector_type(8))) short short8;

__device__ __forceinline__ unsigned short f2bf(float f) {
  unsigned int u = __float_as_uint(f);
  u += 0x7FFFu + ((u >> 16) & 1u);
  return (unsigned short)(u >> 16);
}
__device__ __forceinline__ float bf2f(unsigned short h) {
  return __uint_as_float((unsigned int)h << 16);
}
__device__ __forceinline__ void split2(float v, unsigned short& h, unsigned short& l) {
  h = f2bf(v);
  l = f2bf(v - bf2f(h));
}

#define WAITVM0 asm volatile("s_waitcnt vmcnt(0)" ::: "memory")
#define WAITVM4 asm volatile("s_waitcnt vmcnt(4)" ::: "memory")
#define WAITVM5 asm volatile("s_waitcnt vmcnt(5)" ::: "memory")
#define WAITVM8 asm volatile("s_waitcnt vmcnt(8)" ::: "memory")
#define LGKM0   asm volatile("s_waitcnt lgkmcnt(0)" ::: "memory")
#define SCHED0  __builtin_amdgcn_sched_barrier(0)

// full 8x4 MFMA block (phase 1 / gemmX; fragment set 48 regs, no spill)
#define MFMA_BLOCK(AV, BV)                                                    \
  do {                                                                        \
    __builtin_amdgcn_s_setprio(1);                                            \
    _Pragma("unroll")                                                         \
    for (int m_ = 0; m_ < 8; ++m_) {                                          \
      _Pragma("unroll")                                                       \
      for (int n_ = 0; n_ < 4; ++n_)                                          \
        acc[m_][n_] = __builtin_amdgcn_mfma_f32_16x16x32_bf16(                \
            AV[m_], BV[n_], acc[m_][n_], 0, 0, 0);                            \
    }                                                                         \
    __builtin_amdgcn_s_setprio(0);                                            \
  } while (0)

// half-height (4 m-frags) MFMA: acc rows H*4..H*4+3
#define MFMA_H(AV, BV, H)                                                     \
  do {                                                                        \
    __builtin_amdgcn_s_setprio(1);                                            \
    _Pragma("unroll")                                                         \
    for (int m_ = 0; m_ < 4; ++m_) {                                          \
      _Pragma("unroll")                                                       \
      for (int n_ = 0; n_ < 4; ++n_)                                          \
        acc[(H) * 4 + m_][n_] = __builtin_amdgcn_mfma_f32_16x16x32_bf16(      \
            AV[m_], BV[n_], acc[(H) * 4 + m_][n_], 0, 0, 0);                  \
    }                                                                         \
    __builtin_amdgcn_s_setprio(0);                                            \
  } while (0)

// load 4 A-frags (rows H*64 .. H*64+63) of K-step kt from Cbuf
#define LOADA_H(dst, kt, H)                                                   \
  do {                                                                        \
    _Pragma("unroll")                                                         \
    for (int m_ = 0; m_ < 4; ++m_) {                                          \
      int R_ = (H) * 64 + m_ * 16 + l15;                                      \
      int ph_ = l4 ^ ((R_ >> 1) & 3);                                         \
      dst[m_] = *reinterpret_cast<const bf16x8*>(                             \
          SS + (kt) * 4096 + R_ * 32 + ph_ * 8);                              \
    }                                                                         \
  } while (0)

#define LOADB_G(dst, kt)                                                      \
  do {                                                                        \
    _Pragma("unroll")                                                         \
    for (int n_ = 0; n_ < 4; ++n_)                                            \
      dst[n_] = *reinterpret_cast<const bf16x8*>(bp[n_] + (kt) * 32);         \
  } while (0)

// K=512 layer: A from Cbuf in M-halves (aF0/aF1, 16 regs each), B global->reg
// double-buffered (bE/bO). Live fragments = 64 regs -> fits 128-arch budget
// (acc 128 sits in AGPR half of the 256/thread cap at 2 waves/SIMD).
#define REGB_LAYER(WT)                                                        \
  do {                                                                        \
    _Pragma("unroll")                                                         \
    for (int a_ = 0; a_ < 8; ++a_) {                                          \
      _Pragma("unroll")                                                       \
      for (int b_ = 0; b_ < 4; ++b_)                                          \
        acc[a_][b_] = (f32x4){0.f, 0.f, 0.f, 0.f};                            \
    }                                                                         \
    const unsigned short* bp[4];                                              \
    _Pragma("unroll")                                                         \
    for (int n_ = 0; n_ < 4; ++n_)                                            \
      bp[n_] = (WT) + (size_t)(w * 64 + n_ * 16 + l15) * 512 + l4 * 8;        \
    bf16x8 aF0[4], aF1[4], bE[4], bO[4];                                      \
    LOADB_G(bE, 0);                                                           \
    for (int kk_ = 0; kk_ < 8; ++kk_) {                                       \
      LOADB_G(bO, 2 * kk_ + 1);                                               \
      LOADA_H(aF0, 2 * kk_, 0);                                               \
      LOADA_H(aF1, 2 * kk_, 1);                                               \
      MFMA_H(aF0, bE, 0);                                                     \
      MFMA_H(aF1, bE, 1);                                                     \
      if (kk_ < 7) LOADB_G(bE, 2 * kk_ + 2);                                  \
      LOADA_H(aF0, 2 * kk_ + 1, 0);                                           \
      LOADA_H(aF1, 2 * kk_ + 1, 1);                                           \
      MFMA_H(aF0, bO, 0);                                                     \
      MFMA_H(aF1, bO, 1);                                                     \
    }                                                                         \
  } while (0)

// ---------------------------------------------------------------------------
// gemmF: fused multi-layer GEMM chain. Block = 512 thr (8 waves 1x8),
// M_b = 128 rows, N = 512. Inter-layer activation C lives in LDS "Cbuf"
// (16 segments x [128][32] bf16, slot-swizzled = A-fragment layout, 128 KiB).
// VAR 0 (dense): phase1 de3 (K=256, A=h3 global, ring-3) -> C; phase2 de4
//   (K=512) -> maxout atomic.
// VAR 1 (rel): phase1 r2 (K=512, A synthesized from G on the fly) -> f32
//   out1 + C; phase2 m1 -> C'; phase3 m2 -> f32 out3.
// ---------------------------------------------------------------------------
template<int VAR>
__global__ __launch_bounds__(512, 1)
void gemmF(const unsigned short* __restrict__ Ag,
           const float* __restrict__ G, const float* __restrict__ gb,
           const unsigned short* __restrict__ W1t, const float* __restrict__ b1,
           const unsigned short* __restrict__ W2t, const float* __restrict__ b2,
           const unsigned short* __restrict__ W3t, const float* __restrict__ b3,
           float* __restrict__ out1, float* __restrict__ out3,
           unsigned int* __restrict__ Omax, int m_base)
{
  extern __shared__ __align__(16) char smem[];   // 131072 B
  short* SS = (short*)smem;
  const int tid = threadIdx.x, lane = tid & 63, w = tid >> 6;
  const int l15 = lane & 15, l4 = lane >> 4;
  const int m0 = blockIdx.x * 128;
  constexpr int K1 = VAR ? 512 : 256;
  constexpr int NT1 = K1 / 32;

  f32x4 acc[8][4];
  #pragma unroll
  for (int a = 0; a < 8; ++a)
    #pragma unroll
    for (int b = 0; b < 4; ++b)
      acc[a][b] = (f32x4){0.f, 0.f, 0.f, 0.f};

  // scatter relu(acc+bias) into Cbuf (A-fragment layout, 16 segs x [128][32])
  auto scatterC = [&](const float* bias) {
    float bv[4];
    #pragma unroll
    for (int ni = 0; ni < 4; ++ni) bv[ni] = bias[w * 64 + ni * 16 + l15];
    #pragma unroll
    for (int mi = 0; mi < 8; ++mi)
      #pragma unroll
      for (int i = 0; i < 4; ++i) {
        int row = mi * 16 + l4 * 4 + i;
        #pragma unroll
        for (int ni = 0; ni < 4; ++ni) {
          int col = w * 64 + ni * 16 + l15;
          int c5 = col & 31;
          int ph = (c5 >> 3) ^ ((row >> 1) & 3);
          SS[(col >> 5) * 4096 + row * 32 + ph * 8 + (col & 7)] =
              (short)f2bf(fmaxf(acc[mi][ni][i] + bv[ni], 0.f));
        }
      }
  };

  // coalesced f32 store of acc+bias (no relu) via LDS bounce, 2 halves
  auto bounceOut = [&](float* dst, const float* bias) {
    float* Bf = (float*)smem;
    #pragma unroll
    for (int h = 0; h < 2; ++h) {
      if ((w >> 2) == h) {
        #pragma unroll
        for (int mi = 0; mi < 8; ++mi)
          #pragma unroll
          for (int i = 0; i < 4; ++i) {
            int row = mi * 16 + l4 * 4 + i;
            #pragma unroll
            for (int ni = 0; ni < 4; ++ni) {
              int colh = (w & 3) * 64 + ni * 16 + l15;
              int sl = colh >> 2;
              int ph = (sl & 56) | ((sl & 7) ^ (row & 7));
              Bf[row * 256 + ph * 4 + (colh & 3)] =
                  acc[mi][ni][i] + bias[w * 64 + ni * 16 + l15];
            }
          }
      }
      __syncthreads();
      #pragma unroll
      for (int s = 0; s < 16; ++s) {
        int p = s * 512 + tid;
        int row = p >> 6, sl = p & 63;
        int ph = (sl & 56) | ((sl & 7) ^ (row & 7));
        f32x4 v = *reinterpret_cast<const f32x4*>(&Bf[row * 256 + ph * 4]);
        *reinterpret_cast<f32x4*>(dst + (size_t)(m0 + row) * 512 + h * 256 + sl * 4) = v;
      }
      __syncthreads();
    }
  };

  // ------------------- phase 1: A from global / synthesized -------------------
  const int arow = w * 16 + (lane >> 2);
  const unsigned short* aS = nullptr;
  const float *g1p = nullptr, *g2p = nullptr, *gbp = nullptr;
  if constexpr (VAR == 0) {
    aS = Ag + (size_t)(m0 + arow) * K1 + (((lane & 3) ^ ((arow >> 1) & 3)) * 8);
  } else {
    int r = m0 + arow;
    int b = r & 31, pr = r >> 5;
    int i = pr / 52, j = pr - i * 52;
    g1p = G + (size_t)(i * 32 + b) * 1024 + (lane & 3) * 8;
    g2p = G + (size_t)(j * 32 + b) * 1024 + 512 + (lane & 3) * 8;
    gbp = gb + (lane & 3) * 8;
  }
  const unsigned short* bS1[4];
  #pragma unroll
  for (int o = 0; o < 4; ++o) {
    int br = w * 64 + o * 16 + (lane >> 2);
    bS1[o] = W1t + (size_t)br * K1 + (((lane & 3) ^ ((br >> 1) & 3)) * 8);
  }
  auto stage1 = [&](int kt) {
    short* S = SS + (kt % 3) * 20480;
    if constexpr (VAR == 0) {
      __builtin_amdgcn_global_load_lds(aS + kt * 32, (void*)(S + w * 512), 16, 0, 0);
    } else {
      f32x4 q0 = *reinterpret_cast<const f32x4*>(g1p + kt * 32);
      f32x4 q1 = *reinterpret_cast<const f32x4*>(g1p + kt * 32 + 4);
      f32x4 p0 = *reinterpret_cast<const f32x4*>(g2p + kt * 32);
      f32x4 p1 = *reinterpret_cast<const f32x4*>(g2p + kt * 32 + 4);
      f32x4 c0 = *reinterpret_cast<const f32x4*>(gbp + kt * 32);
      f32x4 c1 = *reinterpret_cast<const f32x4*>(gbp + kt * 32 + 4);
      short8 hv;
      #pragma unroll
      for (int e = 0; e < 4; ++e) {
        hv[e]     = (short)f2bf(fmaxf(q0[e] + p0[e] + c0[e], 0.f));
        hv[4 + e] = (short)f2bf(fmaxf(q1[e] + p1[e] + c1[e], 0.f));
      }
      *reinterpret_cast<short8*>(S + arow * 32 + (((lane & 3) ^ ((arow >> 1) & 3)) * 8)) = hv;
    }
    #pragma unroll
    for (int o = 0; o < 4; ++o)
      __builtin_amdgcn_global_load_lds(bS1[o] + kt * 32,
                                       (void*)(S + 4096 + (w * 64 + o * 16) * 32), 16, 0, 0);
  };

  stage1(0);
  stage1(1);
  #pragma unroll
  for (int kt = 0; kt < NT1; ++kt) {
    LGKM0;
    if (kt < NT1 - 1) { if (VAR) { WAITVM4; } else { WAITVM5; } }
    else { WAITVM0; }
    SCHED0;
    __builtin_amdgcn_s_barrier();
    SCHED0;
    short* S = SS + (kt % 3) * 20480;
    bf16x8 aF[8], bF[4];
    #pragma unroll
    for (int n = 0; n < 4; ++n) {
      int R = w * 64 + n * 16 + l15;
      int ph = l4 ^ ((R >> 1) & 3);
      bF[n] = *reinterpret_cast<const bf16x8*>(S + 4096 + R * 32 + ph * 8);
    }
    #pragma unroll
    for (int m = 0; m < 8; ++m) {
      int R = m * 16 + l15;
      int ph = l4 ^ ((R >> 1) & 3);
      aF[m] = *reinterpret_cast<const bf16x8*>(S + R * 32 + ph * 8);
    }
    if (kt + 2 < NT1) stage1(kt + 2);
    MFMA_BLOCK(aF, bF);
  }
  __syncthreads();

  if constexpr (VAR == 1) bounceOut(out1, b1);   // rel finals (raw +bias)
  scatterC(b1);                                  // C = relu(acc + b1)
  __syncthreads();

  // ------------------- phase 2 -------------------
  REGB_LAYER(W2t);

  if constexpr (VAR == 0) {
    // fused maxout (de4): 128 rows within one object
    int obj = (m_base + m0) >> 10;
    #pragma unroll
    for (int ni = 0; ni < 4; ++ni) {
      int n = w * 64 + ni * 16 + l15;
      float v = acc[0][ni][0];
      #pragma unroll
      for (int mi = 0; mi < 8; ++mi)
        #pragma unroll
        for (int i = 0; i < 4; ++i)
          v = fmaxf(v, acc[mi][ni][i]);
      v = fmaxf(v + b2[n], 0.0f);
      v = fmaxf(v, __shfl_xor(v, 16));
      v = fmaxf(v, __shfl_xor(v, 32));
      if (l4 == 0)
        atomicMax(&Omax[(size_t)obj * 512 + n], __float_as_uint(v));
    }
    return;
  } else {
    __syncthreads();
    scatterC(b2);                                // C' = relu(m1 + b2)
    __syncthreads();
    REGB_LAYER(W3t);                             // m2
    __syncthreads();
    bounceOut(out3, b3);                         // multi finals
  }
}

// ---------------------------------------------------------------------------
// gemmX: 256x256 tile, BK=32, 4-buffer ring, counted vmcnt (round-10 design).
// Used for se2 (K=64, maxout) and de2 (K=128, bf16-plane out).
// ---------------------------------------------------------------------------
template<int COUT, int K>
__global__ __launch_bounds__(512, 1)
void gemmX(const unsigned short* __restrict__ A,
           const unsigned short* __restrict__ Wt,
           const float* __restrict__ bias,
           void* __restrict__ Cdst,
           unsigned int* __restrict__ Omax,
           int ldc, int ntn, int swz8, int m_base)
{
  extern __shared__ __align__(16) char smem[];   // 131072 B

  int bid = blockIdx.x;
  int mt, nt;
  if (swz8) {
    int xcd = bid & 7;
    int slot = bid >> 3;
    nt = slot % ntn;
    mt = (slot / ntn) * 8 + xcd;
  } else {
    mt = bid / ntn;
    nt = bid - mt * ntn;
  }
  const int m0 = mt * 256, n0 = nt * 256;
  const int tid = threadIdx.x;
  const int lane = tid & 63;
  const int w = tid >> 6;
  const int wm = w >> 2, wn = w & 3;
  const int l15 = lane & 15, l4 = lane >> 4;

  const unsigned short* aSrc[2];
  const unsigned short* bSrc[2];
  #pragma unroll
  for (int o = 0; o < 2; ++o) {
    int ar = w * 32 + o * 16 + (lane >> 2);
    int sc = ((lane & 3) ^ ((ar >> 1) & 3)) * 8;
    aSrc[o] = A + (size_t)(m0 + ar) * K + sc;
    bSrc[o] = Wt + (size_t)(n0 + ar) * K + sc;
  }

  f32x4 acc[8][4];
  #pragma unroll
  for (int a = 0; a < 8; ++a)
    #pragma unroll
    for (int b = 0; b < 4; ++b)
      acc[a][b] = (f32x4){0.f, 0.f, 0.f, 0.f};

  constexpr int NT = K / 32;

  auto STAGE = [&](int kt) {
    short* Ab = (short*)(smem + (size_t)(kt & 3) * 32768);
    short* Bb = Ab + 8192;
    int koff = kt * 32;
    #pragma unroll
    for (int o = 0; o < 2; ++o) {
      int rows = w * 32 + o * 16;
      __builtin_amdgcn_global_load_lds(aSrc[o] + koff, (void*)(Ab + rows * 32), 16, 0, 0);
      __builtin_amdgcn_global_load_lds(bSrc[o] + koff, (void*)(Bb + rows * 32), 16, 0, 0);
    }
  };

  STAGE(0);
  if (NT > 1) STAGE(1);
  if (NT > 2) STAGE(2);

  #pragma unroll
  for (int kt = 0; kt < NT; ++kt) {
    const int beyond = (NT - 1 - kt < 2) ? (NT - 1 - kt) : 2;
    if (beyond == 0)      { WAITVM0; }
    else if (beyond == 1) { WAITVM4; }
    else                  { WAITVM8; }
    SCHED0;
    __builtin_amdgcn_s_barrier();
    SCHED0;

    short* Ab = (short*)(smem + (size_t)(kt & 3) * 32768);
    short* Bb = Ab + 8192;

    bf16x8 aF[8], bF[4];
    #pragma unroll
    for (int n = 0; n < 4; ++n) {
      int R = wn * 64 + n * 16 + l15;
      int ph = l4 ^ ((R >> 1) & 3);
      bF[n] = *reinterpret_cast<const bf16x8*>(&Bb[R * 32 + ph * 8]);
    }
    #pragma unroll
    for (int m = 0; m < 8; ++m) {
      int R = wm * 128 + m * 16 + l15;
      int ph = l4 ^ ((R >> 1) & 3);
      aF[m] = *reinterpret_cast<const bf16x8*>(&Ab[R * 32 + ph * 8]);
    }

    if (kt + 3 <= NT - 1) STAGE(kt + 3);

    MFMA_BLOCK(aF, bF);
  }

  __syncthreads();

  if (COUT == 2) {
    int obj = (m_base + m0) >> 10;
    #pragma unroll
    for (int ni = 0; ni < 4; ++ni) {
      int n = n0 + wn * 64 + ni * 16 + l15;
      float v = acc[0][ni][0];
      #pragma unroll
      for (int mi = 0; mi < 8; ++mi)
        #pragma unroll
        for (int i = 0; i < 4; ++i)
          v = fmaxf(v, acc[mi][ni][i]);
      v = fmaxf(v + bias[n], 0.0f);
      v = fmaxf(v, __shfl_xor(v, 16));
      v = fmaxf(v, __shfl_xor(v, 32));
      if (l4 == 0)
        atomicMax(&Omax[(size_t)obj * 512 + n], __float_as_uint(v));
    }
    return;
  }
  // COUT==1: relu bf16 plane via [256][256] bounce
  unsigned short* Bp = (unsigned short*)smem;
  unsigned short* Cp = (unsigned short*)Cdst;
  #pragma unroll
  for (int mi = 0; mi < 8; ++mi)
    #pragma unroll
    for (int i = 0; i < 4; ++i) {
      int row = wm * 128 + mi * 16 + l4 * 4 + i;
      #pragma unroll
      for (int ni = 0; ni < 4; ++ni) {
        int col = wn * 64 + ni * 16 + l15;
        int sl = col >> 3;
        int ph = (sl & 24) | ((sl & 7) ^ (row & 7));
        Bp[row * 256 + ph * 8 + (col & 7)] = f2bf(fmaxf(acc[mi][ni][i] + bias[n0 + col], 0.f));
      }
    }
  __syncthreads();
  #pragma unroll
  for (int s = 0; s < 16; ++s) {
    int p = s * 512 + tid;
    int row = p >> 5, sl = p & 31;
    int ph = (sl & 24) | ((sl & 7) ^ (row & 7));
    short8 v = *reinterpret_cast<const short8*>(&Bp[row * 256 + ph * 8]);
    *reinterpret_cast<short8*>(Cp + (size_t)(m0 + row) * ldc + n0 + sl * 8) = v;
  }
}

// ---------------------------------------------------------------------------
// gemm3: split-2 GEMM (W hi+lo planes), BK=64. Only for the G factor GEMM.
// ---------------------------------------------------------------------------
__global__ __launch_bounds__(256)
void gemm3(const unsigned short* __restrict__ A,
           const unsigned short* __restrict__ Wt,
           const float* __restrict__ bias,
           void* __restrict__ Cdst,
           int M, int K, int ldc, int ntn)
{
  __shared__ __align__(16) short SM[3][128][64];

  int bid = blockIdx.x;
  int mt = bid / ntn, nt = bid - mt * ntn;
  const int m0 = mt * 128, n0 = nt * 128;
  const int tid = threadIdx.x;
  const int lane = tid & 63;
  const int wave = tid >> 6;
  const int wm = wave >> 1, wn = wave & 1;
  const int l15 = lane & 15, l4 = lane >> 4;

  const int rr = tid >> 3;
  const int sp = tid & 7;
  const int sl = sp ^ (rr & 7);
  const int slE = sl * 8;

  const unsigned short* a_p[4];
  const unsigned short* b_p[4];
  #pragma unroll
  for (int c = 0; c < 4; ++c) {
    int rt = c * 32 + rr;
    a_p[c] = A + (size_t)(m0 + rt) * K + slE;
    b_p[c] = Wt + (size_t)(n0 + rt) * 2 * K + slE;
  }

  f32x4 acc[4][4];
  #pragma unroll
  for (int a = 0; a < 4; ++a)
    #pragma unroll
    for (int b = 0; b < 4; ++b)
      acc[a][b] = (f32x4){0.f, 0.f, 0.f, 0.f};

  char* const smb = (char*)&SM[0][0][0];

  for (int k0 = 0; k0 < K; k0 += 64) {
    #pragma unroll
    for (int c = 0; c < 4; ++c) {
      char* lb = smb + c * 4096 + (tid & 192) * 16;
      __builtin_amdgcn_global_load_lds(a_p[c] + k0, (void*)lb, 16, 0, 0);
      __builtin_amdgcn_global_load_lds(b_p[c] + k0, (void*)(lb + 16384), 16, 0, 0);
      __builtin_amdgcn_global_load_lds(b_p[c] + K + k0, (void*)(lb + 32768), 16, 0, 0);
    }
    __syncthreads();
    #pragma unroll
    for (int kf = 0; kf < 2; ++kf) {
      bf16x8 av[4], bh[4], bl[4];
      #pragma unroll
      for (int mi = 0; mi < 4; ++mi) {
        int R = wm * 64 + mi * 16 + l15;
        int sph = (kf * 4 + l4) ^ (R & 7);
        av[mi] = *reinterpret_cast<const bf16x8*>(&SM[0][R][sph * 8]);
      }
      #pragma unroll
      for (int ni = 0; ni < 4; ++ni) {
        int R = wn * 64 + ni * 16 + l15;
        int sph = (kf * 4 + l4) ^ (R & 7);
        bh[ni] = *reinterpret_cast<const bf16x8*>(&SM[1][R][sph * 8]);
        bl[ni] = *reinterpret_cast<const bf16x8*>(&SM[2][R][sph * 8]);
      }
      #pragma unroll
      for (int mi = 0; mi < 4; ++mi)
        #pragma unroll
        for (int ni = 0; ni < 4; ++ni) {
          acc[mi][ni] = __builtin_amdgcn_mfma_f32_16x16x32_bf16(av[mi], bh[ni], acc[mi][ni], 0, 0, 0);
          acc[mi][ni] = __builtin_amdgcn_mfma_f32_16x16x32_bf16(av[mi], bl[ni], acc[mi][ni], 0, 0, 0);
        }
    }
    __syncthreads();
  }

  float* Bf = (float*)smb;
  float* Cf = (float*)Cdst;
  #pragma unroll
  for (int h = 0; h < 2; ++h) {
    if (wm == h) {
      #pragma unroll
      for (int mi = 0; mi < 4; ++mi)
        #pragma unroll
        for (int i = 0; i < 4; ++i) {
          int lr2 = mi * 16 + l4 * 4 + i;
          #pragma unroll
          for (int ni = 0; ni < 4; ++ni) {
            int col = wn * 64 + ni * 16 + l15;
            int off = lr2 * 128 + (((col >> 2) ^ (lr2 & 7)) << 2) + (col & 3);
            Bf[off] = acc[mi][ni][i] + bias[n0 + col];
          }
        }
    }
    __syncthreads();
    #pragma unroll
    for (int s = 0; s < 8; ++s) {
      int p = tid * 8 + s;
      int row = p >> 5, ls = p & 31;
      f32x4 v = *reinterpret_cast<const f32x4*>(&Bf[row * 128 + ((ls ^ (row & 7)) << 2)]);
      *reinterpret_cast<f32x4*>(Cf + (size_t)(m0 + h * 64 + row) * ldc + n0 + ls * 4) = v;
    }
    __syncthreads();
  }
}

// ---------------------------------------------------------------------------
// Per-point MLPs (f32 exact) -> relu'd bf16 planes: s2 [pt][64], h2 [pt][128].
// ---------------------------------------------------------------------------
__global__ __launch_bounds__(256)
void points_kernel(const float* __restrict__ obj6,
                   const float* __restrict__ sW0, const float* __restrict__ sb0,
                   const float* __restrict__ sW1, const float* __restrict__ sb1,
                   const float* __restrict__ dW0, const float* __restrict__ db0,
                   const float* __restrict__ dW1, const float* __restrict__ db1,
                   unsigned short* __restrict__ s2,
                   unsigned short* __restrict__ h2)
{
  __shared__ float sw0[96], sbb0[32], sw1[2048], sbb1[64];
  __shared__ float dw0[384], dbb0[64], dw1[8192], dbb1[128];
  int tid = threadIdx.x;
  for (int i = tid; i < 96; i += 256) sw0[i] = sW0[i];
  if (tid < 32) sbb0[tid] = sb0[tid];
  for (int i = tid; i < 2048; i += 256) sw1[i] = sW1[i];
  if (tid < 64) sbb1[tid] = sb1[tid];
  for (int i = tid; i < 384; i += 256) dw0[i] = dW0[i];
  if (tid < 64) dbb0[tid] = db0[tid];
  for (int i = tid; i < 8192; i += 256) dw1[i] = dW1[i];
  if (tid < 128) dbb1[tid] = db1[tid];
  __syncthreads();

  int pt = blockIdx.x * 256 + tid;
  const float* in = obj6 + (size_t)pt * 6;
  float c0 = in[0], c1 = in[1], c2 = in[2], c3 = in[3], c4 = in[4], c5 = in[5];

  {  // sparse (xyz only)
    float h1[32];
    #pragma unroll
    for (int j = 0; j < 32; ++j)
      h1[j] = fmaxf(c0 * sw0[j] + c1 * sw0[32 + j] + c2 * sw0[64 + j] + sbb0[j], 0.f);
    unsigned short* orow = s2 + (size_t)pt * 64;
    #pragma unroll
    for (int j8 = 0; j8 < 8; ++j8) {
      float a[8];
      #pragma unroll
      for (int e = 0; e < 8; ++e) a[e] = sbb1[j8 * 8 + e];
      #pragma unroll
      for (int i = 0; i < 32; ++i) {
        float hv = h1[i];
        #pragma unroll
        for (int e = 0; e < 8; ++e) a[e] += hv * sw1[i * 64 + j8 * 8 + e];
      }
      short8 o;
      #pragma unroll
      for (int e = 0; e < 8; ++e) o[e] = (short)f2bf(fmaxf(a[e], 0.f));
      *reinterpret_cast<short8*>(orow + j8 * 8) = o;
    }
  }

  {  // dense (all 6 dims)
    float h1[64];
    #pragma unroll
    for (int j = 0; j < 64; ++j) {
      float a = dbb0[j] + c0 * dw0[j] + c1 * dw0[64 + j] + c2 * dw0[128 + j]
              + c3 * dw0[192 + j] + c4 * dw0[256 + j] + c5 * dw0[320 + j];
      h1[j] = fmaxf(a, 0.f);
    }
    unsigned short* orow = h2 + (size_t)pt * 128;
    #pragma unroll
    for (int ch = 0; ch < 4; ++ch) {
      float a[32];
      #pragma unroll
      for (int e = 0; e < 32; ++e) a[e] = dbb1[ch * 32 + e];
      #pragma unroll 8
      for (int i = 0; i < 64; ++i) {
        float hv = h1[i];
        #pragma unroll
        for (int e = 0; e < 32; ++e) a[e] += hv * dw1[i * 128 + ch * 32 + e];
      }
      #pragma unroll
      for (int e8 = 0; e8 < 4; ++e8) {
        short8 o;
        #pragma unroll
        for (int e = 0; e < 8; ++e) o[e] = (short)f2bf(fmaxf(a[e8 * 8 + e], 0.f));
        *reinterpret_cast<short8*>(orow + ch * 32 + e8 * 8) = o;
      }
    }
  }
}

// ---------------------------------------------------------------------------
__global__ void transpose_split(const float* __restrict__ W, unsigned short* __restrict__ Wt,
                                int K, int N)
{
  int id = blockIdx.x * 256 + threadIdx.x;
  if (id >= K * N) return;
  int k = id / N, n = id - k * N;
  unsigned short h, l;
  split2(W[id], h, l);
  Wt[(size_t)n * 2 * K + k] = h;
  Wt[(size_t)n * 2 * K + K + k] = l;
}

__global__ void transpose_cast(const float* __restrict__ W, unsigned short* __restrict__ Wt,
                               int K, int N)
{
  int id = blockIdx.x * 256 + threadIdx.x;
  if (id >= K * N) return;
  int k = id / N, n = id - k * N;
  Wt[(size_t)n * K + k] = f2bf(W[id]);
}

__global__ void zero_kernel(unsigned int* __restrict__ p, int n)
{
  int id = blockIdx.x * 256 + threadIdx.x;
  if (id < n) p[id] = 0u;
}

__global__ void pn_pack_kernel(const float* __restrict__ pnf, unsigned short* __restrict__ pnp)
{
  int id = blockIdx.x * 256 + threadIdx.x;  // 851968
  int o = id >> 9, c = id & 511;
  int b = o / 52, n = o - b * 52;
  pnp[((size_t)(n * 32 + b) << 9) + c] = f2bf(pnf[id]);
}

// ---------------------------------------------------------------------------
__global__ __launch_bounds__(256)
void objmlp_kernel(const float* __restrict__ obj,
                   const float* __restrict__ W0, const float* __restrict__ b0,
                   const float* __restrict__ W1, const float* __restrict__ b1,
                   const float* __restrict__ W2, const float* __restrict__ b2,
                   float* __restrict__ out)
{
  __shared__ float x[512];
  __shared__ float h1[128];
  __shared__ float h2[256];
  int tid = threadIdx.x;
  int r = blockIdx.x;
  int n = r >> 5, b = r & 31;
  int o = b * 52 + n;
  const float* xs = obj + (size_t)o * 512;
  x[tid] = xs[tid];
  x[tid + 256] = xs[tid + 256];
  __syncthreads();
  if (tid < 128) {
    float a = b0[tid];
    #pragma unroll 8
    for (int k = 0; k < 512; ++k) a += x[k] * W0[k * 128 + tid];
    h1[tid] = fmaxf(a, 0.f);
  }
  __syncthreads();
  {
    float a = b1[tid];
    #pragma unroll 8
    for (int k = 0; k < 128; ++k) a += h1[k] * W1[k * 256 + tid];
    h2[tid] = fmaxf(a, 0.f);
  }
  __syncthreads();
  for (int j = tid; j < 607; j += 256) {
    float a = b2[j];
    #pragma unroll 8
    for (int k = 0; k < 256; ++k) a += h2[k] * W2[k * 607 + j];
    out[(size_t)r * 607 + j] = a;
  }
}

// ---------------------------------------------------------------------------
extern "C" void kernel_launch(void* const* d_in, const int* in_sizes, int n_in,
                              void* d_out, int out_size, void* d_ws, size_t ws_size,
                              hipStream_t stream)
{
  const float* objects = (const float*)d_in[1];
  const float* de_W0 = (const float*)d_in[3];  const float* de_b0 = (const float*)d_in[4];
  const float* de_W1 = (const float*)d_in[5];  const float* de_b1 = (const float*)d_in[6];
  const float* de_W2 = (const float*)d_in[7];  const float* de_b2 = (const float*)d_in[8];
  const float* de_W3 = (const float*)d_in[9];  const float* de_b3 = (const float*)d_in[10];
  const float* de_W4 = (const float*)d_in[11]; const float* de_b4 = (const float*)d_in[12];
  const float* se_W0 = (const float*)d_in[13]; const float* se_b0 = (const float*)d_in[14];
  const float* se_W1 = (const float*)d_in[15]; const float* se_b1 = (const float*)d_in[16];
  const float* se_W2 = (const float*)d_in[17]; const float* se_b2 = (const float*)d_in[18];
  const float* om_W0 = (const float*)d_in[19]; const float* om_b0 = (const float*)d_in[20];
  const float* om_W1 = (const float*)d_in[21]; const float* om_b1 = (const float*)d_in[22];
  const float* om_W2 = (const float*)d_in[23]; const float* om_b2 = (const float*)d_in[24];
  const float* r1_W = (const float*)d_in[25];  const float* r1_b = (const float*)d_in[26];
  const float* r2_W = (const float*)d_in[27];  const float* r2_b = (const float*)d_in[28];
  const float* m1_W = (const float*)d_in[29];  const float* m1_b = (const float*)d_in[30];
  const float* m2_W = (const float*)d_in[31];  const float* m2_b = (const float*)d_in[32];
  (void)in_sizes; (void)n_in; (void)out_size; (void)ws_size;

  (void)hipFuncSetAttribute(reinterpret_cast<const void*>(&gemmF<0>),
                            hipFuncAttributeMaxDynamicSharedMemorySize, 131072);
  (void)hipFuncSetAttribute(reinterpret_cast<const void*>(&gemmF<1>),
                            hipFuncAttributeMaxDynamicSharedMemorySize, 131072);
  (void)hipFuncSetAttribute(reinterpret_cast<const void*>(&gemmX<2, 64>),
                            hipFuncAttributeMaxDynamicSharedMemorySize, 131072);
  (void)hipFuncSetAttribute(reinterpret_cast<const void*>(&gemmX<1, 128>),
                            hipFuncAttributeMaxDynamicSharedMemorySize, 131072);

  float* outf = (float*)d_out;
  float* out_obj = outf;                          // [52,32,607]
  float* out_rel = outf + 1010048;                // [52,52,32,512]
  float* out_multi = out_rel + 44302336;

  // ---- workspace (~11 MB) ----
  char* ws = (char*)d_ws;
  size_t off = 0;
  auto alloc = [&](size_t bytes) -> void* {
    void* p = ws + off;
    off += (bytes + 255) & ~(size_t)255;
    return p;
  };
  unsigned short* wt_se2 = (unsigned short*)alloc((size_t)512 * 64 * 2);
  unsigned short* wt_de2 = (unsigned short*)alloc((size_t)256 * 128 * 2);
  unsigned short* wt_de3 = (unsigned short*)alloc((size_t)512 * 256 * 2);
  unsigned short* wt_de4 = (unsigned short*)alloc((size_t)512 * 512 * 2);
  unsigned short* wt_g   = (unsigned short*)alloc((size_t)1024 * 1024 * 2);
  unsigned short* wt_r2  = (unsigned short*)alloc((size_t)512 * 512 * 2);
  unsigned short* wt_m1  = (unsigned short*)alloc((size_t)512 * 512 * 2);
  unsigned short* wt_m2  = (unsigned short*)alloc((size_t)512 * 512 * 2);
  float* zbias = (float*)alloc((size_t)1024 * 4);
  float* Gbuf  = (float*)alloc((size_t)1664 * 1024 * 4);

  // ---- arena inside d_out (rel+multi regions) ----
  char* arena = (char*)out_rel;
  unsigned int* pnmax   = (unsigned int*)(arena);              // 3.4 MB
  float*        obj_f32 = (float*)(arena + 3407872);           // 3.4 MB
  unsigned short* pn_p  = (unsigned short*)(arena + 6815744);  // 1.7 MB
  char* cbuf = arena + 8519680;
  const size_t PC = 212992;                                    // 8 chunks
  unsigned short* s2_c = (unsigned short*)(cbuf);                    // 27.3 MB
  unsigned short* h2_c = (unsigned short*)(cbuf + PC * 128);         // 54.5 MB
  unsigned short* h3_c = (unsigned short*)(cbuf + PC * 384);         // 109  MB

  zero_kernel<<<(2 * 851968) / 256, 256, 0, stream>>>(pnmax, 2 * 851968);
  zero_kernel<<<4, 256, 0, stream>>>((unsigned int*)zbias, 1024);

  auto tsplit = [&](const float* W, unsigned short* Dst, int K, int N) {
    int n = K * N;
    transpose_split<<<(n + 255) / 256, 256, 0, stream>>>(W, Dst, K, N);
  };
  auto tcast = [&](const float* W, unsigned short* Dst, int K, int N) {
    int n = K * N;
    transpose_cast<<<(n + 255) / 256, 256, 0, stream>>>(W, Dst, K, N);
  };
  tcast(se_W2, wt_se2, 64, 512);
  tcast(de_W2, wt_de2, 128, 256);
  tcast(de_W3, wt_de3, 256, 512);
  tcast(de_W4, wt_de4, 512, 512);
  tsplit(r1_W,             wt_g,              512, 512);
  tsplit(r1_W + 512 * 512, wt_g + 512 * 1024, 512, 512);
  tcast(r2_W,  wt_r2, 512, 512);
  tcast(m1_W,  wt_m1, 512, 512);
  tcast(m2_W,  wt_m2, 512, 512);

  // ---- point-cloud chains: 8 chunks x 208 objects (212,992 pts) ----
  for (int c = 0; c < 8; ++c) {
    int base = c * (int)PC;
    points_kernel<<<PC / 256, 256, 0, stream>>>(
        objects + (size_t)base * 6,
        se_W0, se_b0, se_W1, se_b1, de_W0, de_b0, de_W1, de_b1, s2_c, h2_c);
    gemmX<2, 64><<<2 * (PC / 256), 512, 131072, stream>>>(
        s2_c, wt_se2, se_b2, nullptr, pnmax, 512, 2, 1, base);
    gemmX<1, 128><<<(PC / 256), 512, 131072, stream>>>(
        h2_c, wt_de2, de_b2, h3_c, nullptr, 256, 1, 1, 0);
    gemmF<0><<<PC / 128, 512, 131072, stream>>>(
        h3_c, nullptr, nullptr, wt_de3, de_b3, wt_de4, de_b4, nullptr, nullptr,
        nullptr, nullptr, (unsigned int*)obj_f32, base);
  }

  pn_pack_kernel<<<851968 / 256, 256, 0, stream>>>((const float*)pnmax, pn_p);
  objmlp_kernel<<<1664, 256, 0, stream>>>(obj_f32, om_W0, om_b0, om_W1, om_b1,
                                          om_W2, om_b2, out_obj);

  // ---- relation chain ----
  gemm3<<<13 * 8, 256, 0, stream>>>(pn_p, wt_g, zbias, Gbuf, 1664, 512, 1024, 8);
  gemmF<1><<<676, 512, 131072, stream>>>(
      nullptr, Gbuf, r1_b, wt_r2, r2_b, wt_m1, m1_b, wt_m2, m2_b,
      out_rel, out_multi, nullptr, 0);
}

// Round 17
// 3713.759 us; speedup vs baseline: 1.0297x; 1.0107x over previous
//
#include <hip/hip_runtime.h>
#include <stdint.h>

typedef __attribute__((ext_vector_type(8))) __bf16 bf16x8;
typedef __attribute__((ext_vector_type(4))) float f32x4;
typedef __attribute__((ext_vector_type(8))) short short8;

__device__ __forceinline__ unsigned short f2bf(float f) {
  unsigned int u = __float_as_uint(f);
  u += 0x7FFFu + ((u >> 16) & 1u);
  return (unsigned short)(u >> 16);
}
__device__ __forceinline__ float bf2f(unsigned short h) {
  return __uint_as_float((unsigned int)h << 16);
}
__device__ __forceinline__ void split2(float v, unsigned short& h, unsigned short& l) {
  h = f2bf(v);
  l = f2bf(v - bf2f(h));
}

#define WAITVM0 asm volatile("s_waitcnt vmcnt(0)" ::: "memory")
#define WAITVM4 asm volatile("s_waitcnt vmcnt(4)" ::: "memory")
#define WAITVM5 asm volatile("s_waitcnt vmcnt(5)" ::: "memory")
#define WAITVM8 asm volatile("s_waitcnt vmcnt(8)" ::: "memory")
#define LGKM0   asm volatile("s_waitcnt lgkmcnt(0)" ::: "memory")
#define SCHED0  __builtin_amdgcn_sched_barrier(0)

// full 8x4 MFMA block (phase 1 / gemmX; proven-good fragment set)
#define MFMA_BLOCK(AV, BV)                                                    \
  do {                                                                        \
    __builtin_amdgcn_s_setprio(1);                                            \
    _Pragma("unroll")                                                         \
    for (int m_ = 0; m_ < 8; ++m_) {                                          \
      _Pragma("unroll")                                                       \
      for (int n_ = 0; n_ < 4; ++n_)                                          \
        acc[m_][n_] = __builtin_amdgcn_mfma_f32_16x16x32_bf16(                \
            AV[m_], BV[n_], acc[m_][n_], 0, 0, 0);                            \
    }                                                                         \
    __builtin_amdgcn_s_setprio(0);                                            \
  } while (0)

// load all 8 A-frags of K-step kt from Cbuf (A-fragment layout)
#define LOADA_C(dst, kt)                                                      \
  do {                                                                        \
    _Pragma("unroll")                                                         \
    for (int m_ = 0; m_ < 8; ++m_) {                                          \
      int R_ = m_ * 16 + l15;                                                 \
      int ph_ = l4 ^ ((R_ >> 1) & 3);                                         \
      dst[m_] = *reinterpret_cast<const bf16x8*>(                             \
          SS + (kt) * 4096 + R_ * 32 + ph_ * 8);                              \
    }                                                                         \
  } while (0)

// phase-2/3 layer over ONE N-half H (cols w*64 + (2H..2H+1)*16 + l15).
// acc[8][2]=64 regs + aC 32 + bC/bN 16 -> strictly below proven budget.
#define REGB_HALF(WT, H, ACC)                                                 \
  do {                                                                        \
    _Pragma("unroll")                                                         \
    for (int a_ = 0; a_ < 8; ++a_) {                                          \
      ACC[a_][0] = (f32x4){0.f, 0.f, 0.f, 0.f};                               \
      ACC[a_][1] = (f32x4){0.f, 0.f, 0.f, 0.f};                               \
    }                                                                         \
    const unsigned short* bpH0 =                                              \
        (WT) + (size_t)(w * 64 + ((H) * 2 + 0) * 16 + l15) * 512 + l4 * 8;    \
    const unsigned short* bpH1 =                                              \
        (WT) + (size_t)(w * 64 + ((H) * 2 + 1) * 16 + l15) * 512 + l4 * 8;    \
    bf16x8 aC[8], bC0, bC1, bN0, bN1;                                         \
    bC0 = *reinterpret_cast<const bf16x8*>(bpH0);                             \
    bC1 = *reinterpret_cast<const bf16x8*>(bpH1);                             \
    _Pragma("unroll")                                                         \
    for (int kt_ = 0; kt_ < 16; ++kt_) {                                      \
      LOADA_C(aC, kt_);                                                       \
      if (kt_ < 15) {                                                         \
        bN0 = *reinterpret_cast<const bf16x8*>(bpH0 + (kt_ + 1) * 32);        \
        bN1 = *reinterpret_cast<const bf16x8*>(bpH1 + (kt_ + 1) * 32);        \
      }                                                                       \
      __builtin_amdgcn_s_setprio(1);                                          \
      _Pragma("unroll")                                                       \
      for (int m_ = 0; m_ < 8; ++m_) {                                        \
        ACC[m_][0] = __builtin_amdgcn_mfma_f32_16x16x32_bf16(                 \
            aC[m_], bC0, ACC[m_][0], 0, 0, 0);                                \
        ACC[m_][1] = __builtin_amdgcn_mfma_f32_16x16x32_bf16(                 \
            aC[m_], bC1, ACC[m_][1], 0, 0, 0);                                \
      }                                                                       \
      __builtin_amdgcn_s_setprio(0);                                          \
      bC0 = bN0; bC1 = bN1;                                                   \
    }                                                                         \
  } while (0)

// maxout for one N-half: channels n = w*64 + (2H+n_)*16 + l15
#define MAXOUT_H(ACC, H, BIAS)                                                \
  do {                                                                        \
    _Pragma("unroll")                                                         \
    for (int n_ = 0; n_ < 2; ++n_) {                                          \
      int n = w * 64 + ((H) * 2 + n_) * 16 + l15;                             \
      float v = ACC[0][n_][0];                                                \
      _Pragma("unroll")                                                       \
      for (int mi_ = 0; mi_ < 8; ++mi_) {                                     \
        _Pragma("unroll")                                                     \
        for (int i_ = 0; i_ < 4; ++i_)                                        \
          v = fmaxf(v, ACC[mi_][n_][i_]);                                     \
      }                                                                       \
      v = fmaxf(v + (BIAS)[n], 0.0f);                                         \
      v = fmaxf(v, __shfl_xor(v, 16));                                        \
      v = fmaxf(v, __shfl_xor(v, 32));                                        \
      if (l4 == 0)                                                            \
        atomicMax(&Omax[(size_t)obj * 512 + n], __float_as_uint(v));          \
    }                                                                         \
  } while (0)

// scatter one N-half of relu(acc+bias) into Cbuf (A-fragment layout)
#define SCATC_H(ACC, H, BIAS)                                                 \
  do {                                                                        \
    _Pragma("unroll")                                                         \
    for (int mi_ = 0; mi_ < 8; ++mi_) {                                       \
      _Pragma("unroll")                                                       \
      for (int i_ = 0; i_ < 4; ++i_) {                                        \
        int row = mi_ * 16 + l4 * 4 + i_;                                     \
        _Pragma("unroll")                                                     \
        for (int n_ = 0; n_ < 2; ++n_) {                                      \
          int col = w * 64 + ((H) * 2 + n_) * 16 + l15;                       \
          int c5 = col & 31;                                                  \
          int ph = (c5 >> 3) ^ ((row >> 1) & 3);                              \
          SS[(col >> 5) * 4096 + row * 32 + ph * 8 + (col & 7)] =             \
              (short)f2bf(fmaxf(ACC[mi_][n_][i_] + (BIAS)[col], 0.f));        \
        }                                                                     \
      }                                                                       \
    }                                                                         \
  } while (0)

// ---------------------------------------------------------------------------
// gemmF: fused multi-layer GEMM chain. Block = 512 thr (8 waves 1x8),
// M_b = 128 rows, N = 512. Inter-layer activation C lives in LDS "Cbuf"
// (16 segments x [128][32] bf16, slot-swizzled = A-fragment layout, 128 KiB).
// Phase-2/3 layers run as two sequential N-half passes (acc[8][2] each).
// VAR 0 (dense): phase1 de3 (K=256) -> C; phase2 de4 (K=512) -> maxout.
// VAR 1 (rel): phase1 r2 (K=512, A synth from G) -> f32 out1 + C;
//   phase2 m1 -> C'; phase3 m2 -> f32 out3.
// ---------------------------------------------------------------------------
template<int VAR>
__global__ __launch_bounds__(512, 1)
void gemmF(const unsigned short* __restrict__ Ag,
           const float* __restrict__ G, const float* __restrict__ gb,
           const unsigned short* __restrict__ W1t, const float* __restrict__ b1,
           const unsigned short* __restrict__ W2t, const float* __restrict__ b2,
           const unsigned short* __restrict__ W3t, const float* __restrict__ b3,
           float* __restrict__ out1, float* __restrict__ out3,
           unsigned int* __restrict__ Omax, int m_base)
{
  extern __shared__ __align__(16) char smem[];   // 131072 B
  short* SS = (short*)smem;
  const int tid = threadIdx.x, lane = tid & 63, w = tid >> 6;
  const int l15 = lane & 15, l4 = lane >> 4;
  const int m0 = blockIdx.x * 128;
  constexpr int K1 = VAR ? 512 : 256;
  constexpr int NT1 = K1 / 32;

  f32x4 acc[8][4];
  #pragma unroll
  for (int a = 0; a < 8; ++a)
    #pragma unroll
    for (int b = 0; b < 4; ++b)
      acc[a][b] = (f32x4){0.f, 0.f, 0.f, 0.f};

  // scatter relu(acc+bias) into Cbuf (full width, phase-1 epilogue)
  auto scatterC = [&](const float* bias) {
    #pragma unroll
    for (int mi = 0; mi < 8; ++mi)
      #pragma unroll
      for (int i = 0; i < 4; ++i) {
        int row = mi * 16 + l4 * 4 + i;
        #pragma unroll
        for (int ni = 0; ni < 4; ++ni) {
          int col = w * 64 + ni * 16 + l15;
          int c5 = col & 31;
          int ph = (c5 >> 3) ^ ((row >> 1) & 3);
          SS[(col >> 5) * 4096 + row * 32 + ph * 8 + (col & 7)] =
              (short)f2bf(fmaxf(acc[mi][ni][i] + bias[col], 0.f));
        }
      }
  };

  // coalesced f32 store of phase-1 acc (+bias, no relu) via LDS bounce
  auto bounceOut = [&](float* dst, const float* bias) {
    float* Bf = (float*)smem;
    #pragma unroll
    for (int h = 0; h < 2; ++h) {
      if ((w >> 2) == h) {
        #pragma unroll
        for (int mi = 0; mi < 8; ++mi)
          #pragma unroll
          for (int i = 0; i < 4; ++i) {
            int row = mi * 16 + l4 * 4 + i;
            #pragma unroll
            for (int ni = 0; ni < 4; ++ni) {
              int colh = (w & 3) * 64 + ni * 16 + l15;
              int sl = colh >> 2;
              int ph = (sl & 56) | ((sl & 7) ^ (row & 7));
              Bf[row * 256 + ph * 4 + (colh & 3)] =
                  acc[mi][ni][i] + bias[w * 64 + ni * 16 + l15];
            }
          }
      }
      __syncthreads();
      #pragma unroll
      for (int s = 0; s < 16; ++s) {
        int p = s * 512 + tid;
        int row = p >> 6, sl = p & 63;
        int ph = (sl & 56) | ((sl & 7) ^ (row & 7));
        f32x4 v = *reinterpret_cast<const f32x4*>(&Bf[row * 256 + ph * 4]);
        *reinterpret_cast<f32x4*>(dst + (size_t)(m0 + row) * 512 + h * 256 + sl * 4) = v;
      }
      __syncthreads();
    }
  };

  // ------------------- phase 1: A from global / synthesized -------------------
  const int arow = w * 16 + (lane >> 2);
  const unsigned short* aS = nullptr;
  const float *g1p = nullptr, *g2p = nullptr, *gbp = nullptr;
  if constexpr (VAR == 0) {
    aS = Ag + (size_t)(m0 + arow) * K1 + (((lane & 3) ^ ((arow >> 1) & 3)) * 8);
  } else {
    int r = m0 + arow;
    int b = r & 31, pr = r >> 5;
    int i = pr / 52, j = pr - i * 52;
    g1p = G + (size_t)(i * 32 + b) * 1024 + (lane & 3) * 8;
    g2p = G + (size_t)(j * 32 + b) * 1024 + 512 + (lane & 3) * 8;
    gbp = gb + (lane & 3) * 8;
  }
  const unsigned short* bS1[4];
  #pragma unroll
  for (int o = 0; o < 4; ++o) {
    int br = w * 64 + o * 16 + (lane >> 2);
    bS1[o] = W1t + (size_t)br * K1 + (((lane & 3) ^ ((br >> 1) & 3)) * 8);
  }
  auto stage1 = [&](int kt) {
    short* S = SS + (kt % 3) * 20480;
    if constexpr (VAR == 0) {
      __builtin_amdgcn_global_load_lds(aS + kt * 32, (void*)(S + w * 512), 16, 0, 0);
    } else {
      f32x4 q0 = *reinterpret_cast<const f32x4*>(g1p + kt * 32);
      f32x4 q1 = *reinterpret_cast<const f32x4*>(g1p + kt * 32 + 4);
      f32x4 p0 = *reinterpret_cast<const f32x4*>(g2p + kt * 32);
      f32x4 p1 = *reinterpret_cast<const f32x4*>(g2p + kt * 32 + 4);
      f32x4 c0 = *reinterpret_cast<const f32x4*>(gbp + kt * 32);
      f32x4 c1 = *reinterpret_cast<const f32x4*>(gbp + kt * 32 + 4);
      short8 hv;
      #pragma unroll
      for (int e = 0; e < 4; ++e) {
        hv[e]     = (short)f2bf(fmaxf(q0[e] + p0[e] + c0[e], 0.f));
        hv[4 + e] = (short)f2bf(fmaxf(q1[e] + p1[e] + c1[e], 0.f));
      }
      *reinterpret_cast<short8*>(S + arow * 32 + (((lane & 3) ^ ((arow >> 1) & 3)) * 8)) = hv;
    }
    #pragma unroll
    for (int o = 0; o < 4; ++o)
      __builtin_amdgcn_global_load_lds(bS1[o] + kt * 32,
                                       (void*)(S + 4096 + (w * 64 + o * 16) * 32), 16, 0, 0);
  };

  stage1(0);
  stage1(1);
  #pragma unroll
  for (int kt = 0; kt < NT1; ++kt) {
    LGKM0;
    if (kt < NT1 - 1) { if (VAR) { WAITVM4; } else { WAITVM5; } }
    else { WAITVM0; }
    SCHED0;
    __builtin_amdgcn_s_barrier();
    SCHED0;
    short* S = SS + (kt % 3) * 20480;
    bf16x8 aF[8], bF[4];
    #pragma unroll
    for (int n = 0; n < 4; ++n) {
      int R = w * 64 + n * 16 + l15;
      int ph = l4 ^ ((R >> 1) & 3);
      bF[n] = *reinterpret_cast<const bf16x8*>(S + 4096 + R * 32 + ph * 8);
    }
    #pragma unroll
    for (int m = 0; m < 8; ++m) {
      int R = m * 16 + l15;
      int ph = l4 ^ ((R >> 1) & 3);
      aF[m] = *reinterpret_cast<const bf16x8*>(S + R * 32 + ph * 8);
    }
    if (kt + 2 < NT1) stage1(kt + 2);
    MFMA_BLOCK(aF, bF);
  }
  __syncthreads();

  if constexpr (VAR == 1) bounceOut(out1, b1);   // rel finals (raw +bias)
  scatterC(b1);                                  // C = relu(acc + b1)
  __syncthreads();

  if constexpr (VAR == 0) {
    // ---------------- phase 2 (de4): two N-half passes + fused maxout ------
    int obj = (m_base + m0) >> 10;
    f32x4 accH[8][2];
    REGB_HALF(W2t, 0, accH);
    MAXOUT_H(accH, 0, b2);
    REGB_HALF(W2t, 1, accH);
    MAXOUT_H(accH, 1, b2);
    return;
  } else {
    // ---------------- phase 2 (m1): hold both halves, then scatter C' ------
    f32x4 pA[8][2], pB[8][2];
    REGB_HALF(W2t, 0, pA);
    REGB_HALF(W2t, 1, pB);
    __syncthreads();                 // all waves done reading C
    SCATC_H(pA, 0, b2);
    SCATC_H(pB, 1, b2);
    __syncthreads();                 // C' published
    // ---------------- phase 3 (m2): two halves, then f32 bounce ------------
    REGB_HALF(W3t, 0, pA);
    REGB_HALF(W3t, 1, pB);
    __syncthreads();                 // all waves done reading C'
    // bounce both halves: [128][256] f32 per wm-half of rows
    float* Bf = (float*)smem;
    #pragma unroll
    for (int h = 0; h < 2; ++h) {
      if ((w >> 2) == h) {
        #pragma unroll
        for (int mi = 0; mi < 8; ++mi)
          #pragma unroll
          for (int i = 0; i < 4; ++i) {
            int row = mi * 16 + l4 * 4 + i;
            #pragma unroll
            for (int ni = 0; ni < 4; ++ni) {
              int colh = (w & 3) * 64 + ni * 16 + l15;
              int sl = colh >> 2;
              int ph = (sl & 56) | ((sl & 7) ^ (row & 7));
              float av = (ni < 2) ? pA[mi][ni][i] : pB[mi][ni - 2][i];
              Bf[row * 256 + ph * 4 + (colh & 3)] =
                  av + b3[w * 64 + ni * 16 + l15];
            }
          }
      }
      __syncthreads();
      #pragma unroll
      for (int s = 0; s < 16; ++s) {
        int p = s * 512 + tid;
        int row = p >> 6, sl = p & 63;
        int ph = (sl & 56) | ((sl & 7) ^ (row & 7));
        f32x4 v = *reinterpret_cast<const f32x4*>(&Bf[row * 256 + ph * 4]);
        *reinterpret_cast<f32x4*>(out3 + (size_t)(m0 + row) * 512 + h * 256 + sl * 4) = v;
      }
      __syncthreads();
    }
  }
}

// ---------------------------------------------------------------------------
// gemmX: 256x256 tile, BK=32, 4-buffer ring, counted vmcnt (round-10 design).
// Used for se2 (K=64, maxout) and de2 (K=128, bf16-plane out).
// ---------------------------------------------------------------------------
template<int COUT, int K>
__global__ __launch_bounds__(512, 1)
void gemmX(const unsigned short* __restrict__ A,
           const unsigned short* __restrict__ Wt,
           const float* __restrict__ bias,
           void* __restrict__ Cdst,
           unsigned int* __restrict__ Omax,
           int ldc, int ntn, int swz8, int m_base)
{
  extern __shared__ __align__(16) char smem[];   // 131072 B

  int bid = blockIdx.x;
  int mt, nt;
  if (swz8) {
    int xcd = bid & 7;
    int slot = bid >> 3;
    nt = slot % ntn;
    mt = (slot / ntn) * 8 + xcd;
  } else {
    mt = bid / ntn;
    nt = bid - mt * ntn;
  }
  const int m0 = mt * 256, n0 = nt * 256;
  const int tid = threadIdx.x;
  const int lane = tid & 63;
  const int w = tid >> 6;
  const int wm = w >> 2, wn = w & 3;
  const int l15 = lane & 15, l4 = lane >> 4;

  const unsigned short* aSrc[2];
  const unsigned short* bSrc[2];
  #pragma unroll
  for (int o = 0; o < 2; ++o) {
    int ar = w * 32 + o * 16 + (lane >> 2);
    int sc = ((lane & 3) ^ ((ar >> 1) & 3)) * 8;
    aSrc[o] = A + (size_t)(m0 + ar) * K + sc;
    bSrc[o] = Wt + (size_t)(n0 + ar) * K + sc;
  }

  f32x4 acc[8][4];
  #pragma unroll
  for (int a = 0; a < 8; ++a)
    #pragma unroll
    for (int b = 0; b < 4; ++b)
      acc[a][b] = (f32x4){0.f, 0.f, 0.f, 0.f};

  constexpr int NT = K / 32;

  auto STAGE = [&](int kt) {
    short* Ab = (short*)(smem + (size_t)(kt & 3) * 32768);
    short* Bb = Ab + 8192;
    int koff = kt * 32;
    #pragma unroll
    for (int o = 0; o < 2; ++o) {
      int rows = w * 32 + o * 16;
      __builtin_amdgcn_global_load_lds(aSrc[o] + koff, (void*)(Ab + rows * 32), 16, 0, 0);
      __builtin_amdgcn_global_load_lds(bSrc[o] + koff, (void*)(Bb + rows * 32), 16, 0, 0);
    }
  };

  STAGE(0);
  if (NT > 1) STAGE(1);
  if (NT > 2) STAGE(2);

  #pragma unroll
  for (int kt = 0; kt < NT; ++kt) {
    const int beyond = (NT - 1 - kt < 2) ? (NT - 1 - kt) : 2;
    if (beyond == 0)      { WAITVM0; }
    else if (beyond == 1) { WAITVM4; }
    else                  { WAITVM8; }
    SCHED0;
    __builtin_amdgcn_s_barrier();
    SCHED0;

    short* Ab = (short*)(smem + (size_t)(kt & 3) * 32768);
    short* Bb = Ab + 8192;

    bf16x8 aF[8], bF[4];
    #pragma unroll
    for (int n = 0; n < 4; ++n) {
      int R = wn * 64 + n * 16 + l15;
      int ph = l4 ^ ((R >> 1) & 3);
      bF[n] = *reinterpret_cast<const bf16x8*>(&Bb[R * 32 + ph * 8]);
    }
    #pragma unroll
    for (int m = 0; m < 8; ++m) {
      int R = wm * 128 + m * 16 + l15;
      int ph = l4 ^ ((R >> 1) & 3);
      aF[m] = *reinterpret_cast<const bf16x8*>(&Ab[R * 32 + ph * 8]);
    }

    if (kt + 3 <= NT - 1) STAGE(kt + 3);

    MFMA_BLOCK(aF, bF);
  }

  __syncthreads();

  if (COUT == 2) {
    int obj = (m_base + m0) >> 10;
    #pragma unroll
    for (int ni = 0; ni < 4; ++ni) {
      int n = n0 + wn * 64 + ni * 16 + l15;
      float v = acc[0][ni][0];
      #pragma unroll
      for (int mi = 0; mi < 8; ++mi)
        #pragma unroll
        for (int i = 0; i < 4; ++i)
          v = fmaxf(v, acc[mi][ni][i]);
      v = fmaxf(v + bias[n], 0.0f);
      v = fmaxf(v, __shfl_xor(v, 16));
      v = fmaxf(v, __shfl_xor(v, 32));
      if (l4 == 0)
        atomicMax(&Omax[(size_t)obj * 512 + n], __float_as_uint(v));
    }
    return;
  }
  // COUT==1: relu bf16 plane via [256][256] bounce
  unsigned short* Bp = (unsigned short*)smem;
  unsigned short* Cp = (unsigned short*)Cdst;
  #pragma unroll
  for (int mi = 0; mi < 8; ++mi)
    #pragma unroll
    for (int i = 0; i < 4; ++i) {
      int row = wm * 128 + mi * 16 + l4 * 4 + i;
      #pragma unroll
      for (int ni = 0; ni < 4; ++ni) {
        int col = wn * 64 + ni * 16 + l15;
        int sl = col >> 3;
        int ph = (sl & 24) | ((sl & 7) ^ (row & 7));
        Bp[row * 256 + ph * 8 + (col & 7)] = f2bf(fmaxf(acc[mi][ni][i] + bias[n0 + col], 0.f));
      }
    }
  __syncthreads();
  #pragma unroll
  for (int s = 0; s < 16; ++s) {
    int p = s * 512 + tid;
    int row = p >> 5, sl = p & 31;
    int ph = (sl & 24) | ((sl & 7) ^ (row & 7));
    short8 v = *reinterpret_cast<const short8*>(&Bp[row * 256 + ph * 8]);
    *reinterpret_cast<short8*>(Cp + (size_t)(m0 + row) * ldc + n0 + sl * 8) = v;
  }
}

// ---------------------------------------------------------------------------
// gemm3: split-2 GEMM (W hi+lo planes), BK=64. Only for the G factor GEMM.
// ---------------------------------------------------------------------------
__global__ __launch_bounds__(256)
void gemm3(const unsigned short* __restrict__ A,
           const unsigned short* __restrict__ Wt,
           const float* __restrict__ bias,
           void* __restrict__ Cdst,
           int M, int K, int ldc, int ntn)
{
  __shared__ __align__(16) short SM[3][128][64];

  int bid = blockIdx.x;
  int mt = bid / ntn, nt = bid - mt * ntn;
  const int m0 = mt * 128, n0 = nt * 128;
  const int tid = threadIdx.x;
  const int lane = tid & 63;
  const int wave = tid >> 6;
  const int wm = wave >> 1, wn = wave & 1;
  const int l15 = lane & 15, l4 = lane >> 4;

  const int rr = tid >> 3;
  const int sp = tid & 7;
  const int sl = sp ^ (rr & 7);
  const int slE = sl * 8;

  const unsigned short* a_p[4];
  const unsigned short* b_p[4];
  #pragma unroll
  for (int c = 0; c < 4; ++c) {
    int rt = c * 32 + rr;
    a_p[c] = A + (size_t)(m0 + rt) * K + slE;
    b_p[c] = Wt + (size_t)(n0 + rt) * 2 * K + slE;
  }

  f32x4 acc[4][4];
  #pragma unroll
  for (int a = 0; a < 4; ++a)
    #pragma unroll
    for (int b = 0; b < 4; ++b)
      acc[a][b] = (f32x4){0.f, 0.f, 0.f, 0.f};

  char* const smb = (char*)&SM[0][0][0];

  for (int k0 = 0; k0 < K; k0 += 64) {
    #pragma unroll
    for (int c = 0; c < 4; ++c) {
      char* lb = smb + c * 4096 + (tid & 192) * 16;
      __builtin_amdgcn_global_load_lds(a_p[c] + k0, (void*)lb, 16, 0, 0);
      __builtin_amdgcn_global_load_lds(b_p[c] + k0, (void*)(lb + 16384), 16, 0, 0);
      __builtin_amdgcn_global_load_lds(b_p[c] + K + k0, (void*)(lb + 32768), 16, 0, 0);
    }
    __syncthreads();
    #pragma unroll
    for (int kf = 0; kf < 2; ++kf) {
      bf16x8 av[4], bh[4], bl[4];
      #pragma unroll
      for (int mi = 0; mi < 4; ++mi) {
        int R = wm * 64 + mi * 16 + l15;
        int sph = (kf * 4 + l4) ^ (R & 7);
        av[mi] = *reinterpret_cast<const bf16x8*>(&SM[0][R][sph * 8]);
      }
      #pragma unroll
      for (int ni = 0; ni < 4; ++ni) {
        int R = wn * 64 + ni * 16 + l15;
        int sph = (kf * 4 + l4) ^ (R & 7);
        bh[ni] = *reinterpret_cast<const bf16x8*>(&SM[1][R][sph * 8]);
        bl[ni] = *reinterpret_cast<const bf16x8*>(&SM[2][R][sph * 8]);
      }
      #pragma unroll
      for (int mi = 0; mi < 4; ++mi)
        #pragma unroll
        for (int ni = 0; ni < 4; ++ni) {
          acc[mi][ni] = __builtin_amdgcn_mfma_f32_16x16x32_bf16(av[mi], bh[ni], acc[mi][ni], 0, 0, 0);
          acc[mi][ni] = __builtin_amdgcn_mfma_f32_16x16x32_bf16(av[mi], bl[ni], acc[mi][ni], 0, 0, 0);
        }
    }
    __syncthreads();
  }

  float* Bf = (float*)smb;
  float* Cf = (float*)Cdst;
  #pragma unroll
  for (int h = 0; h < 2; ++h) {
    if (wm == h) {
      #pragma unroll
      for (int mi = 0; mi < 4; ++mi)
        #pragma unroll
        for (int i = 0; i < 4; ++i) {
          int lr2 = mi * 16 + l4 * 4 + i;
          #pragma unroll
          for (int ni = 0; ni < 4; ++ni) {
            int col = wn * 64 + ni * 16 + l15;
            int off = lr2 * 128 + (((col >> 2) ^ (lr2 & 7)) << 2) + (col & 3);
            Bf[off] = acc[mi][ni][i] + bias[n0 + col];
          }
        }
    }
    __syncthreads();
    #pragma unroll
    for (int s = 0; s < 8; ++s) {
      int p = tid * 8 + s;
      int row = p >> 5, ls = p & 31;
      f32x4 v = *reinterpret_cast<const f32x4*>(&Bf[row * 128 + ((ls ^ (row & 7)) << 2)]);
      *reinterpret_cast<f32x4*>(Cf + (size_t)(m0 + h * 64 + row) * ldc + n0 + ls * 4) = v;
    }
    __syncthreads();
  }
}

// ---------------------------------------------------------------------------
// Per-point MLPs (f32 exact) -> relu'd bf16 planes: s2 [pt][64], h2 [pt][128].
// ---------------------------------------------------------------------------
__global__ __launch_bounds__(256)
void points_kernel(const float* __restrict__ obj6,
                   const float* __restrict__ sW0, const float* __restrict__ sb0,
                   const float* __restrict__ sW1, const float* __restrict__ sb1,
                   const float* __restrict__ dW0, const float* __restrict__ db0,
                   const float* __restrict__ dW1, const float* __restrict__ db1,
                   unsigned short* __restrict__ s2,
                   unsigned short* __restrict__ h2)
{
  __shared__ float sw0[96], sbb0[32], sw1[2048], sbb1[64];
  __shared__ float dw0[384], dbb0[64], dw1[8192], dbb1[128];
  int tid = threadIdx.x;
  for (int i = tid; i < 96; i += 256) sw0[i] = sW0[i];
  if (tid < 32) sbb0[tid] = sb0[tid];
  for (int i = tid; i < 2048; i += 256) sw1[i] = sW1[i];
  if (tid < 64) sbb1[tid] = sb1[tid];
  for (int i = tid; i < 384; i += 256) dw0[i] = dW0[i];
  if (tid < 64) dbb0[tid] = db0[tid];
  for (int i = tid; i < 8192; i += 256) dw1[i] = dW1[i];
  if (tid < 128) dbb1[tid] = db1[tid];
  __syncthreads();

  int pt = blockIdx.x * 256 + tid;
  const float* in = obj6 + (size_t)pt * 6;
  float c0 = in[0], c1 = in[1], c2 = in[2], c3 = in[3], c4 = in[4], c5 = in[5];

  {  // sparse (xyz only)
    float h1[32];
    #pragma unroll
    for (int j = 0; j < 32; ++j)
      h1[j] = fmaxf(c0 * sw0[j] + c1 * sw0[32 + j] + c2 * sw0[64 + j] + sbb0[j], 0.f);
    unsigned short* orow = s2 + (size_t)pt * 64;
    #pragma unroll
    for (int j8 = 0; j8 < 8; ++j8) {
      float a[8];
      #pragma unroll
      for (int e = 0; e < 8; ++e) a[e] = sbb1[j8 * 8 + e];
      #pragma unroll
      for (int i = 0; i < 32; ++i) {
        float hv = h1[i];
        #pragma unroll
        for (int e = 0; e < 8; ++e) a[e] += hv * sw1[i * 64 + j8 * 8 + e];
      }
      short8 o;
      #pragma unroll
      for (int e = 0; e < 8; ++e) o[e] = (short)f2bf(fmaxf(a[e], 0.f));
      *reinterpret_cast<short8*>(orow + j8 * 8) = o;
    }
  }

  {  // dense (all 6 dims)
    float h1[64];
    #pragma unroll
    for (int j = 0; j < 64; ++j) {
      float a = dbb0[j] + c0 * dw0[j] + c1 * dw0[64 + j] + c2 * dw0[128 + j]
              + c3 * dw0[192 + j] + c4 * dw0[256 + j] + c5 * dw0[320 + j];
      h1[j] = fmaxf(a, 0.f);
    }
    unsigned short* orow = h2 + (size_t)pt * 128;
    #pragma unroll
    for (int ch = 0; ch < 4; ++ch) {
      float a[32];
      #pragma unroll
      for (int e = 0; e < 32; ++e) a[e] = dbb1[ch * 32 + e];
      #pragma unroll 8
      for (int i = 0; i < 64; ++i) {
        float hv = h1[i];
        #pragma unroll
        for (int e = 0; e < 32; ++e) a[e] += hv * dw1[i * 128 + ch * 32 + e];
      }
      #pragma unroll
      for (int e8 = 0; e8 < 4; ++e8) {
        short8 o;
        #pragma unroll
        for (int e = 0; e < 8; ++e) o[e] = (short)f2bf(fmaxf(a[e8 * 8 + e], 0.f));
        *reinterpret_cast<short8*>(orow + ch * 32 + e8 * 8) = o;
      }
    }
  }
}

// ---------------------------------------------------------------------------
__global__ void transpose_split(const float* __restrict__ W, unsigned short* __restrict__ Wt,
                                int K, int N)
{
  int id = blockIdx.x * 256 + threadIdx.x;
  if (id >= K * N) return;
  int k = id / N, n = id - k * N;
  unsigned short h, l;
  split2(W[id], h, l);
  Wt[(size_t)n * 2 * K + k] = h;
  Wt[(size_t)n * 2 * K + K + k] = l;
}

__global__ void transpose_cast(const float* __restrict__ W, unsigned short* __restrict__ Wt,
                               int K, int N)
{
  int id = blockIdx.x * 256 + threadIdx.x;
  if (id >= K * N) return;
  int k = id / N, n = id - k * N;
  Wt[(size_t)n * K + k] = f2bf(W[id]);
}

__global__ void zero_kernel(unsigned int* __restrict__ p, int n)
{
  int id = blockIdx.x * 256 + threadIdx.x;
  if (id < n) p[id] = 0u;
}

__global__ void pn_pack_kernel(const float* __restrict__ pnf, unsigned short* __restrict__ pnp)
{
  int id = blockIdx.x * 256 + threadIdx.x;  // 851968
  int o = id >> 9, c = id & 511;
  int b = o / 52, n = o - b * 52;
  pnp[((size_t)(n * 32 + b) << 9) + c] = f2bf(pnf[id]);
}

// ---------------------------------------------------------------------------
__global__ __launch_bounds__(256)
void objmlp_kernel(const float* __restrict__ obj,
                   const float* __restrict__ W0, const float* __restrict__ b0,
                   const float* __restrict__ W1, const float* __restrict__ b1,
                   const float* __restrict__ W2, const float* __restrict__ b2,
                   float* __restrict__ out)
{
  __shared__ float x[512];
  __shared__ float h1[128];
  __shared__ float h2[256];
  int tid = threadIdx.x;
  int r = blockIdx.x;
  int n = r >> 5, b = r & 31;
  int o = b * 52 + n;
  const float* xs = obj + (size_t)o * 512;
  x[tid] = xs[tid];
  x[tid + 256] = xs[tid + 256];
  __syncthreads();
  if (tid < 128) {
    float a = b0[tid];
    #pragma unroll 8
    for (int k = 0; k < 512; ++k) a += x[k] * W0[k * 128 + tid];
    h1[tid] = fmaxf(a, 0.f);
  }
  __syncthreads();
  {
    float a = b1[tid];
    #pragma unroll 8
    for (int k = 0; k < 128; ++k) a += h1[k] * W1[k * 256 + tid];
    h2[tid] = fmaxf(a, 0.f);
  }
  __syncthreads();
  for (int j = tid; j < 607; j += 256) {
    float a = b2[j];
    #pragma unroll 8
    for (int k = 0; k < 256; ++k) a += h2[k] * W2[k * 607 + j];
    out[(size_t)r * 607 + j] = a;
  }
}

// ---------------------------------------------------------------------------
extern "C" void kernel_launch(void* const* d_in, const int* in_sizes, int n_in,
                              void* d_out, int out_size, void* d_ws, size_t ws_size,
                              hipStream_t stream)
{
  const float* objects = (const float*)d_in[1];
  const float* de_W0 = (const float*)d_in[3];  const float* de_b0 = (const float*)d_in[4];
  const float* de_W1 = (const float*)d_in[5];  const float* de_b1 = (const float*)d_in[6];
  const float* de_W2 = (const float*)d_in[7];  const float* de_b2 = (const float*)d_in[8];
  const float* de_W3 = (const float*)d_in[9];  const float* de_b3 = (const float*)d_in[10];
  const float* de_W4 = (const float*)d_in[11]; const float* de_b4 = (const float*)d_in[12];
  const float* se_W0 = (const float*)d_in[13]; const float* se_b0 = (const float*)d_in[14];
  const float* se_W1 = (const float*)d_in[15]; const float* se_b1 = (const float*)d_in[16];
  const float* se_W2 = (const float*)d_in[17]; const float* se_b2 = (const float*)d_in[18];
  const float* om_W0 = (const float*)d_in[19]; const float* om_b0 = (const float*)d_in[20];
  const float* om_W1 = (const float*)d_in[21]; const float* om_b1 = (const float*)d_in[22];
  const float* om_W2 = (const float*)d_in[23]; const float* om_b2 = (const float*)d_in[24];
  const float* r1_W = (const float*)d_in[25];  const float* r1_b = (const float*)d_in[26];
  const float* r2_W = (const float*)d_in[27];  const float* r2_b = (const float*)d_in[28];
  const float* m1_W = (const float*)d_in[29];  const float* m1_b = (const float*)d_in[30];
  const float* m2_W = (const float*)d_in[31];  const float* m2_b = (const float*)d_in[32];
  (void)in_sizes; (void)n_in; (void)out_size; (void)ws_size;

  (void)hipFuncSetAttribute(reinterpret_cast<const void*>(&gemmF<0>),
                            hipFuncAttributeMaxDynamicSharedMemorySize, 131072);
  (void)hipFuncSetAttribute(reinterpret_cast<const void*>(&gemmF<1>),
                            hipFuncAttributeMaxDynamicSharedMemorySize, 131072);
  (void)hipFuncSetAttribute(reinterpret_cast<const void*>(&gemmX<2, 64>),
                            hipFuncAttributeMaxDynamicSharedMemorySize, 131072);
  (void)hipFuncSetAttribute(reinterpret_cast<const void*>(&gemmX<1, 128>),
                            hipFuncAttributeMaxDynamicSharedMemorySize, 131072);

  float* outf = (float*)d_out;
  float* out_obj = outf;                          // [52,32,607]
  float* out_rel = outf + 1010048;                // [52,52,32,512]
  float* out_multi = out_rel + 44302336;

  // ---- workspace (~11 MB) ----
  char* ws = (char*)d_ws;
  size_t off = 0;
  auto alloc = [&](size_t bytes) -> void* {
    void* p = ws + off;
    off += (bytes + 255) & ~(size_t)255;
    return p;
  };
  unsigned short* wt_se2 = (unsigned short*)alloc((size_t)512 * 64 * 2);
  unsigned short* wt_de2 = (unsigned short*)alloc((size_t)256 * 128 * 2);
  unsigned short* wt_de3 = (unsigned short*)alloc((size_t)512 * 256 * 2);
  unsigned short* wt_de4 = (unsigned short*)alloc((size_t)512 * 512 * 2);
  unsigned short* wt_g   = (unsigned short*)alloc((size_t)1024 * 1024 * 2);
  unsigned short* wt_r2  = (unsigned short*)alloc((size_t)512 * 512 * 2);
  unsigned short* wt_m1  = (unsigned short*)alloc((size_t)512 * 512 * 2);
  unsigned short* wt_m2  = (unsigned short*)alloc((size_t)512 * 512 * 2);
  float* zbias = (float*)alloc((size_t)1024 * 4);
  float* Gbuf  = (float*)alloc((size_t)1664 * 1024 * 4);

  // ---- arena inside d_out (rel+multi regions) ----
  char* arena = (char*)out_rel;
  unsigned int* pnmax   = (unsigned int*)(arena);              // 3.4 MB
  float*        obj_f32 = (float*)(arena + 3407872);           // 3.4 MB
  unsigned short* pn_p  = (unsigned short*)(arena + 6815744);  // 1.7 MB
  char* cbuf = arena + 8519680;
  const size_t PC = 212992;                                    // 8 chunks
  unsigned short* s2_c = (unsigned short*)(cbuf);                    // 27.3 MB
  unsigned short* h2_c = (unsigned short*)(cbuf + PC * 128);         // 54.5 MB
  unsigned short* h3_c = (unsigned short*)(cbuf + PC * 384);         // 109  MB

  zero_kernel<<<(2 * 851968) / 256, 256, 0, stream>>>(pnmax, 2 * 851968);
  zero_kernel<<<4, 256, 0, stream>>>((unsigned int*)zbias, 1024);

  auto tsplit = [&](const float* W, unsigned short* Dst, int K, int N) {
    int n = K * N;
    transpose_split<<<(n + 255) / 256, 256, 0, stream>>>(W, Dst, K, N);
  };
  auto tcast = [&](const float* W, unsigned short* Dst, int K, int N) {
    int n = K * N;
    transpose_cast<<<(n + 255) / 256, 256, 0, stream>>>(W, Dst, K, N);
  };
  tcast(se_W2, wt_se2, 64, 512);
  tcast(de_W2, wt_de2, 128, 256);
  tcast(de_W3, wt_de3, 256, 512);
  tcast(de_W4, wt_de4, 512, 512);
  tsplit(r1_W,             wt_g,              512, 512);
  tsplit(r1_W + 512 * 512, wt_g + 512 * 1024, 512, 512);
  tcast(r2_W,  wt_r2, 512, 512);
  tcast(m1_W,  wt_m1, 512, 512);
  tcast(m2_W,  wt_m2, 512, 512);

  // ---- point-cloud chains: 8 chunks x 208 objects (212,992 pts) ----
  for (int c = 0; c < 8; ++c) {
    int base = c * (int)PC;
    points_kernel<<<PC / 256, 256, 0, stream>>>(
        objects + (size_t)base * 6,
        se_W0, se_b0, se_W1, se_b1, de_W0, de_b0, de_W1, de_b1, s2_c, h2_c);
    gemmX<2, 64><<<2 * (PC / 256), 512, 131072, stream>>>(
        s2_c, wt_se2, se_b2, nullptr, pnmax, 512, 2, 1, base);
    gemmX<1, 128><<<(PC / 256), 512, 131072, stream>>>(
        h2_c, wt_de2, de_b2, h3_c, nullptr, 256, 1, 1, 0);
    gemmF<0><<<PC / 128, 512, 131072, stream>>>(
        h3_c, nullptr, nullptr, wt_de3, de_b3, wt_de4, de_b4, nullptr, nullptr,
        nullptr, nullptr, (unsigned int*)obj_f32, base);
  }

  pn_pack_kernel<<<851968 / 256, 256, 0, stream>>>((const float*)pnmax, pn_p);
  objmlp_kernel<<<1664, 256, 0, stream>>>(obj_f32, om_W0, om_b0, om_W1, om_b1,
                                          om_W2, om_b2, out_obj);

  // ---- relation chain ----
  gemm3<<<13 * 8, 256, 0, stream>>>(pn_p, wt_g, zbias, Gbuf, 1664, 512, 1024, 8);
  gemmF<1><<<676, 512, 131072, stream>>>(
      nullptr, Gbuf, r1_b, wt_r2, r2_b, wt_m1, m1_b, wt_m2, m2_b,
      out_rel, out_multi, nullptr, 0);
}

// Round 18
// 3521.958 us; speedup vs baseline: 1.0858x; 1.0545x over previous
//
#include <hip/hip_runtime.h>
#include <stdint.h>

typedef __attribute__((ext_vector_type(8))) __bf16 bf16x8;
typedef __attribute__((ext_vector_type(4))) float f32x4;
typedef __attribute__((ext_vector_type(8))) short short8;

__device__ __forceinline__ unsigned short f2bf(float f) {
  unsigned int u = __float_as_uint(f);
  u += 0x7FFFu + ((u >> 16) & 1u);
  return (unsigned short)(u >> 16);
}
__device__ __forceinline__ float bf2f(unsigned short h) {
  return __uint_as_float((unsigned int)h << 16);
}
__device__ __forceinline__ void split2(float v, unsigned short& h, unsigned short& l) {
  h = f2bf(v);
  l = f2bf(v - bf2f(h));
}

#define WAITVM0 asm volatile("s_waitcnt vmcnt(0)" ::: "memory")
#define WAITVM4 asm volatile("s_waitcnt vmcnt(4)" ::: "memory")
#define WAITVM5 asm volatile("s_waitcnt vmcnt(5)" ::: "memory")
#define WAITVM8 asm volatile("s_waitcnt vmcnt(8)" ::: "memory")
#define LGKM0   asm volatile("s_waitcnt lgkmcnt(0)" ::: "memory")
#define SCHED0  __builtin_amdgcn_sched_barrier(0)

// MFMA on NAMED arrays with compile-time indices (no pointer decay)
#define MFMA_BLOCK(AV, BV)                                                    \
  do {                                                                        \
    __builtin_amdgcn_s_setprio(1);                                            \
    _Pragma("unroll")                                                         \
    for (int m_ = 0; m_ < 8; ++m_) {                                          \
      _Pragma("unroll")                                                       \
      for (int n_ = 0; n_ < 4; ++n_)                                          \
        acc[m_][n_] = __builtin_amdgcn_mfma_f32_16x16x32_bf16(                \
            AV[m_], BV[n_], acc[m_][n_], 0, 0, 0);                            \
    }                                                                         \
    __builtin_amdgcn_s_setprio(0);                                            \
  } while (0)

// ---------------------------------------------------------------------------
// gemmF: fused multi-layer GEMM chain (r12 structure, OOB-fixed, unroll-1).
// Block = 512 thr (8 waves 1x8), M_b = 128 rows, N = 512.
// Cbuf: 16 segments x [128][32] bf16 (A-fragment layout), LDS bytes 0..128K.
// Phase-2/3 per-wave B slots: LDS bytes 128K..160K (smem = 163840 B).
// VAR 0 (dense): phase1 de3 (K=256, ring-3) -> C; phase2 de4 -> maxout.
// VAR 1 (rel): phase1 r2 (K=512, A synth from G) -> f32 out1 + C;
//   phase2 m1 -> C'; phase3 m2 -> f32 out3.
// ---------------------------------------------------------------------------
template<int VAR>
__global__ __launch_bounds__(512, 1)
void gemmF(const unsigned short* __restrict__ Ag,
           const float* __restrict__ G, const float* __restrict__ gb,
           const unsigned short* __restrict__ W1t, const float* __restrict__ b1,
           const unsigned short* __restrict__ W2t, const float* __restrict__ b2,
           const unsigned short* __restrict__ W3t, const float* __restrict__ b3,
           float* __restrict__ out1, float* __restrict__ out3,
           unsigned int* __restrict__ Omax, int m_base)
{
  extern __shared__ __align__(16) char smem[];   // 163840 B
  short* SS = (short*)smem;
  const int tid = threadIdx.x, lane = tid & 63, w = tid >> 6;
  const int l15 = lane & 15, l4 = lane >> 4;
  const int m0 = blockIdx.x * 128;
  constexpr int K1 = VAR ? 512 : 256;
  constexpr int NT1 = K1 / 32;

  f32x4 acc[8][4];
  #pragma unroll
  for (int a = 0; a < 8; ++a)
    #pragma unroll
    for (int b = 0; b < 4; ++b)
      acc[a][b] = (f32x4){0.f, 0.f, 0.f, 0.f};

  // scatter relu(acc+bias) into Cbuf (A-fragment layout)
  auto scatterC = [&](const float* bias) {
    #pragma unroll
    for (int mi = 0; mi < 8; ++mi)
      #pragma unroll
      for (int i = 0; i < 4; ++i) {
        int row = mi * 16 + l4 * 4 + i;
        #pragma unroll
        for (int ni = 0; ni < 4; ++ni) {
          int col = w * 64 + ni * 16 + l15;
          int c5 = col & 31;
          int ph = (c5 >> 3) ^ ((row >> 1) & 3);
          SS[(col >> 5) * 4096 + row * 32 + ph * 8 + (col & 7)] =
              (short)f2bf(fmaxf(acc[mi][ni][i] + bias[col], 0.f));
        }
      }
  };

  // coalesced f32 store of acc+bias (no relu) via LDS bounce, 2 halves
  auto bounceOut = [&](float* dst, const float* bias) {
    float* Bf = (float*)smem;
    #pragma unroll
    for (int h = 0; h < 2; ++h) {
      if ((w >> 2) == h) {
        #pragma unroll
        for (int mi = 0; mi < 8; ++mi)
          #pragma unroll
          for (int i = 0; i < 4; ++i) {
            int row = mi * 16 + l4 * 4 + i;
            #pragma unroll
            for (int ni = 0; ni < 4; ++ni) {
              int colh = (w & 3) * 64 + ni * 16 + l15;
              int sl = colh >> 2;
              int ph = (sl & 56) | ((sl & 7) ^ (row & 7));
              Bf[row * 256 + ph * 4 + (colh & 3)] =
                  acc[mi][ni][i] + bias[w * 64 + ni * 16 + l15];
            }
          }
      }
      __syncthreads();
      #pragma unroll
      for (int s = 0; s < 16; ++s) {
        int p = s * 512 + tid;
        int row = p >> 6, sl = p & 63;
        int ph = (sl & 56) | ((sl & 7) ^ (row & 7));
        f32x4 v = *reinterpret_cast<const f32x4*>(&Bf[row * 256 + ph * 4]);
        *reinterpret_cast<f32x4*>(dst + (size_t)(m0 + row) * 512 + h * 256 + sl * 4) = v;
      }
      __syncthreads();
    }
  };

  // K=512 layer: A from Cbuf, per-wave single-buffered B slot in upper LDS.
  auto ldsA_loop = [&](const unsigned short* Wt) {
    #pragma unroll
    for (int a = 0; a < 8; ++a)
      #pragma unroll
      for (int b = 0; b < 4; ++b)
        acc[a][b] = (f32x4){0.f, 0.f, 0.f, 0.f};
    short* myB = SS + 65536 + w * 2048;          // bytes 131072 + w*4096
    const unsigned short* bS[4];
    #pragma unroll
    for (int o = 0; o < 4; ++o) {
      int br = w * 64 + o * 16 + (lane >> 2);
      bS[o] = Wt + (size_t)br * 512 + (((lane & 3) ^ ((br >> 1) & 3)) * 8);
    }
    #pragma unroll 1
    for (int kt = 0; kt < 16; ++kt) {
      LGKM0; SCHED0;                      // prior myB ds_reads retired
      #pragma unroll
      for (int o = 0; o < 4; ++o)
        __builtin_amdgcn_global_load_lds(bS[o] + kt * 32, (void*)(myB + o * 512), 16, 0, 0);
      bf16x8 aF[8], bF[4];
      #pragma unroll
      for (int m = 0; m < 8; ++m) {       // A reads overlap B's L2 latency
        int R = m * 16 + l15;
        int ph = l4 ^ ((R >> 1) & 3);
        aF[m] = *reinterpret_cast<const bf16x8*>(SS + kt * 4096 + R * 32 + ph * 8);
      }
      WAITVM0; SCHED0;
      #pragma unroll
      for (int n = 0; n < 4; ++n) {
        int Rl = n * 16 + l15;
        int ph = l4 ^ ((Rl >> 1) & 3);
        bF[n] = *reinterpret_cast<const bf16x8*>(myB + Rl * 32 + ph * 8);
      }
      MFMA_BLOCK(aF, bF);
    }
  };

  // ------------------- phase 1: A from global / synthesized -------------------
  const int arow = w * 16 + (lane >> 2);
  const unsigned short* aS = nullptr;
  const float *g1p = nullptr, *g2p = nullptr, *gbp = nullptr;
  if constexpr (VAR == 0) {
    aS = Ag + (size_t)(m0 + arow) * K1 + (((lane & 3) ^ ((arow >> 1) & 3)) * 8);
  } else {
    int r = m0 + arow;
    int b = r & 31, pr = r >> 5;
    int i = pr / 52, j = pr - i * 52;
    g1p = G + (size_t)(i * 32 + b) * 1024 + (lane & 3) * 8;
    g2p = G + (size_t)(j * 32 + b) * 1024 + 512 + (lane & 3) * 8;
    gbp = gb + (lane & 3) * 8;
  }
  const unsigned short* bS1[4];
  #pragma unroll
  for (int o = 0; o < 4; ++o) {
    int br = w * 64 + o * 16 + (lane >> 2);
    bS1[o] = W1t + (size_t)br * K1 + (((lane & 3) ^ ((br >> 1) & 3)) * 8);
  }
  auto stage1 = [&](int kt) {
    short* S = SS + (kt % 3) * 20480;
    if constexpr (VAR == 0) {
      __builtin_amdgcn_global_load_lds(aS + kt * 32, (void*)(S + w * 512), 16, 0, 0);
    } else {
      f32x4 q0 = *reinterpret_cast<const f32x4*>(g1p + kt * 32);
      f32x4 q1 = *reinterpret_cast<const f32x4*>(g1p + kt * 32 + 4);
      f32x4 p0 = *reinterpret_cast<const f32x4*>(g2p + kt * 32);
      f32x4 p1 = *reinterpret_cast<const f32x4*>(g2p + kt * 32 + 4);
      f32x4 c0 = *reinterpret_cast<const f32x4*>(gbp + kt * 32);
      f32x4 c1 = *reinterpret_cast<const f32x4*>(gbp + kt * 32 + 4);
      short8 hv;
      #pragma unroll
      for (int e = 0; e < 4; ++e) {
        hv[e]     = (short)f2bf(fmaxf(q0[e] + p0[e] + c0[e], 0.f));
        hv[4 + e] = (short)f2bf(fmaxf(q1[e] + p1[e] + c1[e], 0.f));
      }
      *reinterpret_cast<short8*>(S + arow * 32 + (((lane & 3) ^ ((arow >> 1) & 3)) * 8)) = hv;
    }
    #pragma unroll
    for (int o = 0; o < 4; ++o)
      __builtin_amdgcn_global_load_lds(bS1[o] + kt * 32,
                                       (void*)(S + 4096 + (w * 64 + o * 16) * 32), 16, 0, 0);
  };

  stage1(0);
  stage1(1);
  #pragma unroll 1
  for (int kt = 0; kt < NT1; ++kt) {
    LGKM0;
    if (kt < NT1 - 1) { if (VAR) { WAITVM4; } else { WAITVM5; } }
    else { WAITVM0; }
    SCHED0;
    __builtin_amdgcn_s_barrier();
    SCHED0;
    short* S = SS + (kt % 3) * 20480;
    bf16x8 aF[8], bF[4];
    #pragma unroll
    for (int n = 0; n < 4; ++n) {
      int R = w * 64 + n * 16 + l15;
      int ph = l4 ^ ((R >> 1) & 3);
      bF[n] = *reinterpret_cast<const bf16x8*>(S + 4096 + R * 32 + ph * 8);
    }
    #pragma unroll
    for (int m = 0; m < 8; ++m) {
      int R = m * 16 + l15;
      int ph = l4 ^ ((R >> 1) & 3);
      aF[m] = *reinterpret_cast<const bf16x8*>(S + R * 32 + ph * 8);
    }
    if (kt + 2 < NT1) stage1(kt + 2);
    MFMA_BLOCK(aF, bF);
  }
  __syncthreads();

  if constexpr (VAR == 1) bounceOut(out1, b1);   // rel finals (raw +bias)
  scatterC(b1);                                  // C = relu(acc + b1)
  __syncthreads();

  // ------------------- phase 2 -------------------
  ldsA_loop(W2t);

  if constexpr (VAR == 0) {
    // fused maxout (de4): 128 rows within one object
    int obj = (m_base + m0) >> 10;
    #pragma unroll
    for (int ni = 0; ni < 4; ++ni) {
      int n = w * 64 + ni * 16 + l15;
      float v = acc[0][ni][0];
      #pragma unroll
      for (int mi = 0; mi < 8; ++mi)
        #pragma unroll
        for (int i = 0; i < 4; ++i)
          v = fmaxf(v, acc[mi][ni][i]);
      v = fmaxf(v + b2[n], 0.0f);
      v = fmaxf(v, __shfl_xor(v, 16));
      v = fmaxf(v, __shfl_xor(v, 32));
      if (l4 == 0)
        atomicMax(&Omax[(size_t)obj * 512 + n], __float_as_uint(v));
    }
    return;
  } else {
    __syncthreads();
    scatterC(b2);                                // C' = relu(m1 + b2)
    __syncthreads();
    ldsA_loop(W3t);                              // m2
    __syncthreads();
    bounceOut(out3, b3);                         // multi finals
  }
}

// ---------------------------------------------------------------------------
// gemmX: 256x256 tile, BK=32, 4-buffer ring, counted vmcnt (round-10 design).
// Used for se2 (K=64, maxout) and de2 (K=128, bf16-plane out).
// ---------------------------------------------------------------------------
template<int COUT, int K>
__global__ __launch_bounds__(512, 1)
void gemmX(const unsigned short* __restrict__ A,
           const unsigned short* __restrict__ Wt,
           const float* __restrict__ bias,
           void* __restrict__ Cdst,
           unsigned int* __restrict__ Omax,
           int ldc, int ntn, int swz8, int m_base)
{
  extern __shared__ __align__(16) char smem[];   // 131072 B

  int bid = blockIdx.x;
  int mt, nt;
  if (swz8) {
    int xcd = bid & 7;
    int slot = bid >> 3;
    nt = slot % ntn;
    mt = (slot / ntn) * 8 + xcd;
  } else {
    mt = bid / ntn;
    nt = bid - mt * ntn;
  }
  const int m0 = mt * 256, n0 = nt * 256;
  const int tid = threadIdx.x;
  const int lane = tid & 63;
  const int w = tid >> 6;
  const int wm = w >> 2, wn = w & 3;
  const int l15 = lane & 15, l4 = lane >> 4;

  const unsigned short* aSrc[2];
  const unsigned short* bSrc[2];
  #pragma unroll
  for (int o = 0; o < 2; ++o) {
    int ar = w * 32 + o * 16 + (lane >> 2);
    int sc = ((lane & 3) ^ ((ar >> 1) & 3)) * 8;
    aSrc[o] = A + (size_t)(m0 + ar) * K + sc;
    bSrc[o] = Wt + (size_t)(n0 + ar) * K + sc;
  }

  f32x4 acc[8][4];
  #pragma unroll
  for (int a = 0; a < 8; ++a)
    #pragma unroll
    for (int b = 0; b < 4; ++b)
      acc[a][b] = (f32x4){0.f, 0.f, 0.f, 0.f};

  constexpr int NT = K / 32;

  auto STAGE = [&](int kt) {
    short* Ab = (short*)(smem + (size_t)(kt & 3) * 32768);
    short* Bb = Ab + 8192;
    int koff = kt * 32;
    #pragma unroll
    for (int o = 0; o < 2; ++o) {
      int rows = w * 32 + o * 16;
      __builtin_amdgcn_global_load_lds(aSrc[o] + koff, (void*)(Ab + rows * 32), 16, 0, 0);
      __builtin_amdgcn_global_load_lds(bSrc[o] + koff, (void*)(Bb + rows * 32), 16, 0, 0);
    }
  };

  STAGE(0);
  if (NT > 1) STAGE(1);
  if (NT > 2) STAGE(2);

  #pragma unroll
  for (int kt = 0; kt < NT; ++kt) {
    const int beyond = (NT - 1 - kt < 2) ? (NT - 1 - kt) : 2;
    if (beyond == 0)      { WAITVM0; }
    else if (beyond == 1) { WAITVM4; }
    else                  { WAITVM8; }
    SCHED0;
    __builtin_amdgcn_s_barrier();
    SCHED0;

    short* Ab = (short*)(smem + (size_t)(kt & 3) * 32768);
    short* Bb = Ab + 8192;

    bf16x8 aF[8], bF[4];
    #pragma unroll
    for (int n = 0; n < 4; ++n) {
      int R = wn * 64 + n * 16 + l15;
      int ph = l4 ^ ((R >> 1) & 3);
      bF[n] = *reinterpret_cast<const bf16x8*>(&Bb[R * 32 + ph * 8]);
    }
    #pragma unroll
    for (int m = 0; m < 8; ++m) {
      int R = wm * 128 + m * 16 + l15;
      int ph = l4 ^ ((R >> 1) & 3);
      aF[m] = *reinterpret_cast<const bf16x8*>(&Ab[R * 32 + ph * 8]);
    }

    if (kt + 3 <= NT - 1) STAGE(kt + 3);

    MFMA_BLOCK(aF, bF);
  }

  __syncthreads();

  if (COUT == 2) {
    int obj = (m_base + m0) >> 10;
    #pragma unroll
    for (int ni = 0; ni < 4; ++ni) {
      int n = n0 + wn * 64 + ni * 16 + l15;
      float v = acc[0][ni][0];
      #pragma unroll
      for (int mi = 0; mi < 8; ++mi)
        #pragma unroll
        for (int i = 0; i < 4; ++i)
          v = fmaxf(v, acc[mi][ni][i]);
      v = fmaxf(v + bias[n], 0.0f);
      v = fmaxf(v, __shfl_xor(v, 16));
      v = fmaxf(v, __shfl_xor(v, 32));
      if (l4 == 0)
        atomicMax(&Omax[(size_t)obj * 512 + n], __float_as_uint(v));
    }
    return;
  }
  // COUT==1: relu bf16 plane via [256][256] bounce
  unsigned short* Bp = (unsigned short*)smem;
  unsigned short* Cp = (unsigned short*)Cdst;
  #pragma unroll
  for (int mi = 0; mi < 8; ++mi)
    #pragma unroll
    for (int i = 0; i < 4; ++i) {
      int row = wm * 128 + mi * 16 + l4 * 4 + i;
      #pragma unroll
      for (int ni = 0; ni < 4; ++ni) {
        int col = wn * 64 + ni * 16 + l15;
        int sl = col >> 3;
        int ph = (sl & 24) | ((sl & 7) ^ (row & 7));
        Bp[row * 256 + ph * 8 + (col & 7)] = f2bf(fmaxf(acc[mi][ni][i] + bias[n0 + col], 0.f));
      }
    }
  __syncthreads();
  #pragma unroll
  for (int s = 0; s < 16; ++s) {
    int p = s * 512 + tid;
    int row = p >> 5, sl = p & 31;
    int ph = (sl & 24) | ((sl & 7) ^ (row & 7));
    short8 v = *reinterpret_cast<const short8*>(&Bp[row * 256 + ph * 8]);
    *reinterpret_cast<short8*>(Cp + (size_t)(m0 + row) * ldc + n0 + sl * 8) = v;
  }
}

// ---------------------------------------------------------------------------
// gemm3: split-2 GEMM (W hi+lo planes), BK=64. Only for the G factor GEMM.
// ---------------------------------------------------------------------------
__global__ __launch_bounds__(256)
void gemm3(const unsigned short* __restrict__ A,
           const unsigned short* __restrict__ Wt,
           const float* __restrict__ bias,
           void* __restrict__ Cdst,
           int M, int K, int ldc, int ntn)
{
  __shared__ __align__(16) short SM[3][128][64];

  int bid = blockIdx.x;
  int mt = bid / ntn, nt = bid - mt * ntn;
  const int m0 = mt * 128, n0 = nt * 128;
  const int tid = threadIdx.x;
  const int lane = tid & 63;
  const int wave = tid >> 6;
  const int wm = wave >> 1, wn = wave & 1;
  const int l15 = lane & 15, l4 = lane >> 4;

  const int rr = tid >> 3;
  const int sp = tid & 7;
  const int sl = sp ^ (rr & 7);
  const int slE = sl * 8;

  const unsigned short* a_p[4];
  const unsigned short* b_p[4];
  #pragma unroll
  for (int c = 0; c < 4; ++c) {
    int rt = c * 32 + rr;
    a_p[c] = A + (size_t)(m0 + rt) * K + slE;
    b_p[c] = Wt + (size_t)(n0 + rt) * 2 * K + slE;
  }

  f32x4 acc[4][4];
  #pragma unroll
  for (int a = 0; a < 4; ++a)
    #pragma unroll
    for (int b = 0; b < 4; ++b)
      acc[a][b] = (f32x4){0.f, 0.f, 0.f, 0.f};

  char* const smb = (char*)&SM[0][0][0];

  for (int k0 = 0; k0 < K; k0 += 64) {
    #pragma unroll
    for (int c = 0; c < 4; ++c) {
      char* lb = smb + c * 4096 + (tid & 192) * 16;
      __builtin_amdgcn_global_load_lds(a_p[c] + k0, (void*)lb, 16, 0, 0);
      __builtin_amdgcn_global_load_lds(b_p[c] + k0, (void*)(lb + 16384), 16, 0, 0);
      __builtin_amdgcn_global_load_lds(b_p[c] + K + k0, (void*)(lb + 32768), 16, 0, 0);
    }
    __syncthreads();
    #pragma unroll
    for (int kf = 0; kf < 2; ++kf) {
      bf16x8 av[4], bh[4], bl[4];
      #pragma unroll
      for (int mi = 0; mi < 4; ++mi) {
        int R = wm * 64 + mi * 16 + l15;
        int sph = (kf * 4 + l4) ^ (R & 7);
        av[mi] = *reinterpret_cast<const bf16x8*>(&SM[0][R][sph * 8]);
      }
      #pragma unroll
      for (int ni = 0; ni < 4; ++ni) {
        int R = wn * 64 + ni * 16 + l15;
        int sph = (kf * 4 + l4) ^ (R & 7);
        bh[ni] = *reinterpret_cast<const bf16x8*>(&SM[1][R][sph * 8]);
        bl[ni] = *reinterpret_cast<const bf16x8*>(&SM[2][R][sph * 8]);
      }
      #pragma unroll
      for (int mi = 0; mi < 4; ++mi)
        #pragma unroll
        for (int ni = 0; ni < 4; ++ni) {
          acc[mi][ni] = __builtin_amdgcn_mfma_f32_16x16x32_bf16(av[mi], bh[ni], acc[mi][ni], 0, 0, 0);
          acc[mi][ni] = __builtin_amdgcn_mfma_f32_16x16x32_bf16(av[mi], bl[ni], acc[mi][ni], 0, 0, 0);
        }
    }
    __syncthreads();
  }

  float* Bf = (float*)smb;
  float* Cf = (float*)Cdst;
  #pragma unroll
  for (int h = 0; h < 2; ++h) {
    if (wm == h) {
      #pragma unroll
      for (int mi = 0; mi < 4; ++mi)
        #pragma unroll
        for (int i = 0; i < 4; ++i) {
          int lr2 = mi * 16 + l4 * 4 + i;
          #pragma unroll
          for (int ni = 0; ni < 4; ++ni) {
            int col = wn * 64 + ni * 16 + l15;
            int off = lr2 * 128 + (((col >> 2) ^ (lr2 & 7)) << 2) + (col & 3);
            Bf[off] = acc[mi][ni][i] + bias[n0 + col];
          }
        }
    }
    __syncthreads();
    #pragma unroll
    for (int s = 0; s < 8; ++s) {
      int p = tid * 8 + s;
      int row = p >> 5, ls = p & 31;
      f32x4 v = *reinterpret_cast<const f32x4*>(&Bf[row * 128 + ((ls ^ (row & 7)) << 2)]);
      *reinterpret_cast<f32x4*>(Cf + (size_t)(m0 + h * 64 + row) * ldc + n0 + ls * 4) = v;
    }
    __syncthreads();
  }
}

// ---------------------------------------------------------------------------
// Per-point MLPs (f32 exact) -> relu'd bf16 planes: s2 [pt][64], h2 [pt][128].
// ---------------------------------------------------------------------------
__global__ __launch_bounds__(256)
void points_kernel(const float* __restrict__ obj6,
                   const float* __restrict__ sW0, const float* __restrict__ sb0,
                   const float* __restrict__ sW1, const float* __restrict__ sb1,
                   const float* __restrict__ dW0, const float* __restrict__ db0,
                   const float* __restrict__ dW1, const float* __restrict__ db1,
                   unsigned short* __restrict__ s2,
                   unsigned short* __restrict__ h2)
{
  __shared__ float sw0[96], sbb0[32], sw1[2048], sbb1[64];
  __shared__ float dw0[384], dbb0[64], dw1[8192], dbb1[128];
  int tid = threadIdx.x;
  for (int i = tid; i < 96; i += 256) sw0[i] = sW0[i];
  if (tid < 32) sbb0[tid] = sb0[tid];
  for (int i = tid; i < 2048; i += 256) sw1[i] = sW1[i];
  if (tid < 64) sbb1[tid] = sb1[tid];
  for (int i = tid; i < 384; i += 256) dw0[i] = dW0[i];
  if (tid < 64) dbb0[tid] = db0[tid];
  for (int i = tid; i < 8192; i += 256) dw1[i] = dW1[i];
  if (tid < 128) dbb1[tid] = db1[tid];
  __syncthreads();

  int pt = blockIdx.x * 256 + tid;
  const float* in = obj6 + (size_t)pt * 6;
  float c0 = in[0], c1 = in[1], c2 = in[2], c3 = in[3], c4 = in[4], c5 = in[5];

  {  // sparse (xyz only)
    float h1[32];
    #pragma unroll
    for (int j = 0; j < 32; ++j)
      h1[j] = fmaxf(c0 * sw0[j] + c1 * sw0[32 + j] + c2 * sw0[64 + j] + sbb0[j], 0.f);
    unsigned short* orow = s2 + (size_t)pt * 64;
    #pragma unroll
    for (int j8 = 0; j8 < 8; ++j8) {
      float a[8];
      #pragma unroll
      for (int e = 0; e < 8; ++e) a[e] = sbb1[j8 * 8 + e];
      #pragma unroll
      for (int i = 0; i < 32; ++i) {
        float hv = h1[i];
        #pragma unroll
        for (int e = 0; e < 8; ++e) a[e] += hv * sw1[i * 64 + j8 * 8 + e];
      }
      short8 o;
      #pragma unroll
      for (int e = 0; e < 8; ++e) o[e] = (short)f2bf(fmaxf(a[e], 0.f));
      *reinterpret_cast<short8*>(orow + j8 * 8) = o;
    }
  }

  {  // dense (all 6 dims)
    float h1[64];
    #pragma unroll
    for (int j = 0; j < 64; ++j) {
      float a = dbb0[j] + c0 * dw0[j] + c1 * dw0[64 + j] + c2 * dw0[128 + j]
              + c3 * dw0[192 + j] + c4 * dw0[256 + j] + c5 * dw0[320 + j];
      h1[j] = fmaxf(a, 0.f);
    }
    unsigned short* orow = h2 + (size_t)pt * 128;
    #pragma unroll
    for (int ch = 0; ch < 4; ++ch) {
      float a[32];
      #pragma unroll
      for (int e = 0; e < 32; ++e) a[e] = dbb1[ch * 32 + e];
      #pragma unroll 8
      for (int i = 0; i < 64; ++i) {
        float hv = h1[i];
        #pragma unroll
        for (int e = 0; e < 32; ++e) a[e] += hv * dw1[i * 128 + ch * 32 + e];
      }
      #pragma unroll
      for (int e8 = 0; e8 < 4; ++e8) {
        short8 o;
        #pragma unroll
        for (int e = 0; e < 8; ++e) o[e] = (short)f2bf(fmaxf(a[e8 * 8 + e], 0.f));
        *reinterpret_cast<short8*>(orow + ch * 32 + e8 * 8) = o;
      }
    }
  }
}

// ---------------------------------------------------------------------------
__global__ void transpose_split(const float* __restrict__ W, unsigned short* __restrict__ Wt,
                                int K, int N)
{
  int id = blockIdx.x * 256 + threadIdx.x;
  if (id >= K * N) return;
  int k = id / N, n = id - k * N;
  unsigned short h, l;
  split2(W[id], h, l);
  Wt[(size_t)n * 2 * K + k] = h;
  Wt[(size_t)n * 2 * K + K + k] = l;
}

__global__ void transpose_cast(const float* __restrict__ W, unsigned short* __restrict__ Wt,
                               int K, int N)
{
  int id = blockIdx.x * 256 + threadIdx.x;
  if (id >= K * N) return;
  int k = id / N, n = id - k * N;
  Wt[(size_t)n * K + k] = f2bf(W[id]);
}

__global__ void zero_kernel(unsigned int* __restrict__ p, int n)
{
  int id = blockIdx.x * 256 + threadIdx.x;
  if (id < n) p[id] = 0u;
}

__global__ void pn_pack_kernel(const float* __restrict__ pnf, unsigned short* __restrict__ pnp)
{
  int id = blockIdx.x * 256 + threadIdx.x;  // 851968
  int o = id >> 9, c = id & 511;
  int b = o / 52, n = o - b * 52;
  pnp[((size_t)(n * 32 + b) << 9) + c] = f2bf(pnf[id]);
}

// ---------------------------------------------------------------------------
__global__ __launch_bounds__(256)
void objmlp_kernel(const float* __restrict__ obj,
                   const float* __restrict__ W0, const float* __restrict__ b0,
                   const float* __restrict__ W1, const float* __restrict__ b1,
                   const float* __restrict__ W2, const float* __restrict__ b2,
                   float* __restrict__ out)
{
  __shared__ float x[512];
  __shared__ float h1[128];
  __shared__ float h2[256];
  int tid = threadIdx.x;
  int r = blockIdx.x;
  int n = r >> 5, b = r & 31;
  int o = b * 52 + n;
  const float* xs = obj + (size_t)o * 512;
  x[tid] = xs[tid];
  x[tid + 256] = xs[tid + 256];
  __syncthreads();
  if (tid < 128) {
    float a = b0[tid];
    #pragma unroll 8
    for (int k = 0; k < 512; ++k) a += x[k] * W0[k * 128 + tid];
    h1[tid] = fmaxf(a, 0.f);
  }
  __syncthreads();
  {
    float a = b1[tid];
    #pragma unroll 8
    for (int k = 0; k < 128; ++k) a += h1[k] * W1[k * 256 + tid];
    h2[tid] = fmaxf(a, 0.f);
  }
  __syncthreads();
  for (int j = tid; j < 607; j += 256) {
    float a = b2[j];
    #pragma unroll 8
    for (int k = 0; k < 256; ++k) a += h2[k] * W2[k * 607 + j];
    out[(size_t)r * 607 + j] = a;
  }
}

// ---------------------------------------------------------------------------
extern "C" void kernel_launch(void* const* d_in, const int* in_sizes, int n_in,
                              void* d_out, int out_size, void* d_ws, size_t ws_size,
                              hipStream_t stream)
{
  const float* objects = (const float*)d_in[1];
  const float* de_W0 = (const float*)d_in[3];  const float* de_b0 = (const float*)d_in[4];
  const float* de_W1 = (const float*)d_in[5];  const float* de_b1 = (const float*)d_in[6];
  const float* de_W2 = (const float*)d_in[7];  const float* de_b2 = (const float*)d_in[8];
  const float* de_W3 = (const float*)d_in[9];  const float* de_b3 = (const float*)d_in[10];
  const float* de_W4 = (const float*)d_in[11]; const float* de_b4 = (const float*)d_in[12];
  const float* se_W0 = (const float*)d_in[13]; const float* se_b0 = (const float*)d_in[14];
  const float* se_W1 = (const float*)d_in[15]; const float* se_b1 = (const float*)d_in[16];
  const float* se_W2 = (const float*)d_in[17]; const float* se_b2 = (const float*)d_in[18];
  const float* om_W0 = (const float*)d_in[19]; const float* om_b0 = (const float*)d_in[20];
  const float* om_W1 = (const float*)d_in[21]; const float* om_b1 = (const float*)d_in[22];
  const float* om_W2 = (const float*)d_in[23]; const float* om_b2 = (const float*)d_in[24];
  const float* r1_W = (const float*)d_in[25];  const float* r1_b = (const float*)d_in[26];
  const float* r2_W = (const float*)d_in[27];  const float* r2_b = (const float*)d_in[28];
  const float* m1_W = (const float*)d_in[29];  const float* m1_b = (const float*)d_in[30];
  const float* m2_W = (const float*)d_in[31];  const float* m2_b = (const float*)d_in[32];
  (void)in_sizes; (void)n_in; (void)out_size; (void)ws_size;

  (void)hipFuncSetAttribute(reinterpret_cast<const void*>(&gemmF<0>),
                            hipFuncAttributeMaxDynamicSharedMemorySize, 163840);
  (void)hipFuncSetAttribute(reinterpret_cast<const void*>(&gemmF<1>),
                            hipFuncAttributeMaxDynamicSharedMemorySize, 163840);
  (void)hipFuncSetAttribute(reinterpret_cast<const void*>(&gemmX<2, 64>),
                            hipFuncAttributeMaxDynamicSharedMemorySize, 131072);
  (void)hipFuncSetAttribute(reinterpret_cast<const void*>(&gemmX<1, 128>),
                            hipFuncAttributeMaxDynamicSharedMemorySize, 131072);

  float* outf = (float*)d_out;
  float* out_obj = outf;                          // [52,32,607]
  float* out_rel = outf + 1010048;                // [52,52,32,512]
  float* out_multi = out_rel + 44302336;

  // ---- workspace (~11 MB) ----
  char* ws = (char*)d_ws;
  size_t off = 0;
  auto alloc = [&](size_t bytes) -> void* {
    void* p = ws + off;
    off += (bytes + 255) & ~(size_t)255;
    return p;
  };
  unsigned short* wt_se2 = (unsigned short*)alloc((size_t)512 * 64 * 2);
  unsigned short* wt_de2 = (unsigned short*)alloc((size_t)256 * 128 * 2);
  unsigned short* wt_de3 = (unsigned short*)alloc((size_t)512 * 256 * 2);
  unsigned short* wt_de4 = (unsigned short*)alloc((size_t)512 * 512 * 2);
  unsigned short* wt_g   = (unsigned short*)alloc((size_t)1024 * 1024 * 2);
  unsigned short* wt_r2  = (unsigned short*)alloc((size_t)512 * 512 * 2);
  unsigned short* wt_m1  = (unsigned short*)alloc((size_t)512 * 512 * 2);
  unsigned short* wt_m2  = (unsigned short*)alloc((size_t)512 * 512 * 2);
  float* zbias = (float*)alloc((size_t)1024 * 4);
  float* Gbuf  = (float*)alloc((size_t)1664 * 1024 * 4);

  // ---- arena inside d_out (rel+multi regions) ----
  char* arena = (char*)out_rel;
  unsigned int* pnmax   = (unsigned int*)(arena);              // 3.4 MB
  float*        obj_f32 = (float*)(arena + 3407872);           // 3.4 MB
  unsigned short* pn_p  = (unsigned short*)(arena + 6815744);  // 1.7 MB
  char* cbuf = arena + 8519680;
  const size_t PC = 212992;                                    // 8 chunks
  unsigned short* s2_c = (unsigned short*)(cbuf);                    // 27.3 MB
  unsigned short* h2_c = (unsigned short*)(cbuf + PC * 128);         // 54.5 MB
  unsigned short* h3_c = (unsigned short*)(cbuf + PC * 384);         // 109  MB

  zero_kernel<<<(2 * 851968) / 256, 256, 0, stream>>>(pnmax, 2 * 851968);
  zero_kernel<<<4, 256, 0, stream>>>((unsigned int*)zbias, 1024);

  auto tsplit = [&](const float* W, unsigned short* Dst, int K, int N) {
    int n = K * N;
    transpose_split<<<(n + 255) / 256, 256, 0, stream>>>(W, Dst, K, N);
  };
  auto tcast = [&](const float* W, unsigned short* Dst, int K, int N) {
    int n = K * N;
    transpose_cast<<<(n + 255) / 256, 256, 0, stream>>>(W, Dst, K, N);
  };
  tcast(se_W2, wt_se2, 64, 512);
  tcast(de_W2, wt_de2, 128, 256);
  tcast(de_W3, wt_de3, 256, 512);
  tcast(de_W4, wt_de4, 512, 512);
  tsplit(r1_W,             wt_g,              512, 512);
  tsplit(r1_W + 512 * 512, wt_g + 512 * 1024, 512, 512);
  tcast(r2_W,  wt_r2, 512, 512);
  tcast(m1_W,  wt_m1, 512, 512);
  tcast(m2_W,  wt_m2, 512, 512);

  // ---- point-cloud chains: 8 chunks x 208 objects (212,992 pts) ----
  for (int c = 0; c < 8; ++c) {
    int base = c * (int)PC;
    points_kernel<<<PC / 256, 256, 0, stream>>>(
        objects + (size_t)base * 6,
        se_W0, se_b0, se_W1, se_b1, de_W0, de_b0, de_W1, de_b1, s2_c, h2_c);
    gemmX<2, 64><<<2 * (PC / 256), 512, 131072, stream>>>(
        s2_c, wt_se2, se_b2, nullptr, pnmax, 512, 2, 1, base);
    gemmX<1, 128><<<(PC / 256), 512, 131072, stream>>>(
        h2_c, wt_de2, de_b2, h3_c, nullptr, 256, 1, 1, 0);
    gemmF<0><<<PC / 128, 512, 163840, stream>>>(
        h3_c, nullptr, nullptr, wt_de3, de_b3, wt_de4, de_b4, nullptr, nullptr,
        nullptr, nullptr, (unsigned int*)obj_f32, base);
  }

  pn_pack_kernel<<<851968 / 256, 256, 0, stream>>>((const float*)pnmax, pn_p);
  objmlp_kernel<<<1664, 256, 0, stream>>>(obj_f32, om_W0, om_b0, om_W1, om_b1,
                                          om_W2, om_b2, out_obj);

  // ---- relation chain ----
  gemm3<<<13 * 8, 256, 0, stream>>>(pn_p, wt_g, zbias, Gbuf, 1664, 512, 1024, 8);
  gemmF<1><<<676, 512, 163840, stream>>>(
      nullptr, Gbuf, r1_b, wt_r2, r2_b, wt_m1, m1_b, wt_m2, m2_b,
      out_rel, out_multi, nullptr, 0);
}